// Round 2
// baseline (6721.493 us; speedup 1.0000x reference)
//
#include <hip/hip_runtime.h>
#include <math.h>

#define NB   2
#define NS   2048
#define NEMB 1024
#define NH   16
#define NHD  64

static __device__ __forceinline__ float wave_max(float v) {
#pragma unroll
    for (int off = 32; off > 0; off >>= 1)
        v = fmaxf(v, __shfl_xor(v, off, 64));
    return v;
}
static __device__ __forceinline__ float wave_sum(float v) {
#pragma unroll
    for (int off = 32; off > 0; off >>= 1)
        v += __shfl_xor(v, off, 64);
    return v;
}

// ---------------------------------------------------------------------------
// Kernel 1: per-head QKV projection.
// grid = B*H*(S/256), block = 256 (4 waves; each wave = one s-row group lane e)
// Weights for head h staged in LDS, padded to 65 to avoid bank conflicts.
// ---------------------------------------------------------------------------
__global__ __launch_bounds__(256) void qkv_proj(
    const float* __restrict__ X, const float* __restrict__ Z,
    const float* __restrict__ Wq, const float* __restrict__ bq,
    const float* __restrict__ Wk, const float* __restrict__ bk,
    const float* __restrict__ Wv, const float* __restrict__ bv,
    float* __restrict__ Q, float* __restrict__ K, float* __restrict__ V)
{
    const int SCH = NS / 256;       // 8 s-chunks per (b,h)
    int blk    = blockIdx.x;
    int schunk = blk % SCH;
    int h      = (blk / SCH) % NH;
    int b      = blk / (SCH * NH);

    __shared__ float wq[64 * 65], wk[64 * 65], wv[64 * 65];
    __shared__ float bqs[64], bks[64], bvs[64];
    __shared__ float xs[4][64], zs[4][64];

    int t = threadIdx.x;
    for (int j = t; j < 4096; j += 256) {
        int e = j >> 6, d = j & 63;
        wq[e * 65 + d] = Wq[h * 4096 + j];
        wk[e * 65 + d] = Wk[h * 4096 + j];
        wv[e * 65 + d] = Wv[h * 4096 + j];
    }
    if (t < 64) {
        bqs[t] = bq[h * 64 + t];
        bks[t] = bk[h * 64 + t];
        bvs[t] = bv[h * 64 + t];
    }
    __syncthreads();

    int rg = t >> 6;     // wave id = row within 4-row group
    int e  = t & 63;     // output channel
    int s0 = schunk * 256;

    for (int it = 0; it < 64; ++it) {
        int s = s0 + it * 4 + rg;
        // X is [B,S,EMB]; head-h slice is X[b][s][h*64 + d]
        xs[rg][e] = X[(size_t)(b * NS + s) * NEMB + h * 64 + e];
        zs[rg][e] = Z[(size_t)(b * NS + s) * NEMB + h * 64 + e];
        __syncthreads();
        float aq = bqs[e], ak = bks[e], av = bvs[e];
#pragma unroll
        for (int d = 0; d < 64; ++d) {
            float xv = xs[rg][d], zv = zs[rg][d];
            aq = fmaf(wq[e * 65 + d], xv, aq);
            ak = fmaf(wk[e * 65 + d], zv, ak);
            av = fmaf(wv[e * 65 + d], zv, av);
        }
        size_t o = ((size_t)(b * NH + h) * NS + s) * NHD + e;  // [B,H,S,HD]
        Q[o] = aq; K[o] = ak; V[o] = av;
        __syncthreads();
    }
}

// ---------------------------------------------------------------------------
// Kernel 2: flash-style causal attention, fp32.
// grid = (S/64, B*H), block = 256 (4 waves). Block owns 64 q-rows; waves
// interleave rows (row = r*4 + wave) for diagonal-tile load balance.
// Score phase: lane = k. PV phase: lane = d. Online softmax per row.
// ---------------------------------------------------------------------------
__global__ __launch_bounds__(256) void flash_attn(
    const float* __restrict__ Q, const float* __restrict__ K,
    const float* __restrict__ V, float* __restrict__ A)
{
    int qt = blockIdx.x;            // q tile index (64 rows)
    int bh = blockIdx.y;            // b*H + h
    int h  = bh % NH, b = bh / NH;

    __shared__ float qs[64][65];
    __shared__ float ks[64][65];
    __shared__ float vs[64][65];
    __shared__ float ps[4][64];

    int t    = threadIdx.x;
    int w    = t >> 6;
    int lane = t & 63;

    const float* Qb = Q + (size_t)bh * NS * NHD;
    const float* Kb = K + (size_t)bh * NS * NHD;
    const float* Vb = V + (size_t)bh * NS * NHD;

    int q0 = qt * 64;
    for (int j = t; j < 4096; j += 256) {
        int r = j >> 6, d = j & 63;
        qs[r][d] = Qb[(size_t)q0 * 64 + j];
    }

    float acc[16], m[16], l[16];
#pragma unroll
    for (int r = 0; r < 16; ++r) { acc[r] = 0.f; m[r] = -1e30f; l[r] = 0.f; }

    int nt = qt + 1;                // causal: kv tiles 0..qt
    for (int kt = 0; kt < nt; ++kt) {
        __syncthreads();
        for (int j = t; j < 4096; j += 256) {
            int r = j >> 6, d = j & 63;
            ks[r][d] = Kb[(size_t)kt * 4096 + j];
            vs[r][d] = Vb[(size_t)kt * 4096 + j];
        }
        __syncthreads();
        bool diag = (kt == qt);
#pragma unroll
        for (int r = 0; r < 16; ++r) {
            int row  = r * 4 + w;
            int qrow = q0 + row;
            // ---- scores: lane = key index within tile ----
            float s = 0.f;
#pragma unroll
            for (int d = 0; d < 64; ++d)
                s = fmaf(qs[row][d], ks[lane][d], s);
            s *= 0.125f;                       // 1/sqrt(64)
            if (diag && (kt * 64 + lane) > qrow) s = -1e30f;

            float cm   = wave_max(s);
            float mnew = fmaxf(m[r], cm);
            float p    = __expf(s - mnew);
            float csum = wave_sum(p);
            float alpha = __expf(m[r] - mnew);
            l[r] = l[r] * alpha + csum;
            m[r] = mnew;
            ps[w][lane] = p;                   // wave-local handoff
            // ---- PV: lane = output dim d ----
            float a = acc[r] * alpha;
#pragma unroll
            for (int k = 0; k < 64; ++k)
                a = fmaf(ps[w][k], vs[k][lane], a);
            acc[r] = a;
        }
    }
    // epilogue: A is [B,S,EMB] with head-contiguous channels
#pragma unroll
    for (int r = 0; r < 16; ++r) {
        int qrow = q0 + r * 4 + w;
        A[(size_t)(b * NS + qrow) * NEMB + h * 64 + lane] = acc[r] / l[r];
    }
}

// ---------------------------------------------------------------------------
// Kernel 3: Y = A @ Wo^T + bo.  M=4096, N=1024, K=1024.
// BM=BN=64, BK=16, 256 threads, 4x4 micro-tile per thread.
// ---------------------------------------------------------------------------
__global__ __launch_bounds__(256) void out_gemm(
    const float* __restrict__ Aw, const float* __restrict__ Wo,
    const float* __restrict__ bo, float* __restrict__ Y)
{
    int m0 = blockIdx.x * 64;
    int n0 = blockIdx.y * 64;
    __shared__ float As[16][65];
    __shared__ float Bs[16][65];

    int t  = threadIdx.x;
    int tx = t & 15, ty = t >> 4;

    float acc[4][4];
#pragma unroll
    for (int i = 0; i < 4; ++i)
#pragma unroll
        for (int j = 0; j < 4; ++j) acc[i][j] = 0.f;

    int r  = t >> 2;       // row within tile (0..63)
    int qq = t & 3;        // which float4 along k

    for (int k0 = 0; k0 < 1024; k0 += 16) {
        __syncthreads();
        float4 av = *(const float4*)&Aw[(size_t)(m0 + r) * 1024 + k0 + qq * 4];
        As[qq * 4 + 0][r] = av.x; As[qq * 4 + 1][r] = av.y;
        As[qq * 4 + 2][r] = av.z; As[qq * 4 + 3][r] = av.w;
        float4 bv = *(const float4*)&Wo[(size_t)(n0 + r) * 1024 + k0 + qq * 4];
        Bs[qq * 4 + 0][r] = bv.x; Bs[qq * 4 + 1][r] = bv.y;
        Bs[qq * 4 + 2][r] = bv.z; Bs[qq * 4 + 3][r] = bv.w;
        __syncthreads();
#pragma unroll
        for (int kk = 0; kk < 16; ++kk) {
            float a[4], bb[4];
#pragma unroll
            for (int i = 0; i < 4; ++i) a[i]  = As[kk][ty * 4 + i];
#pragma unroll
            for (int j = 0; j < 4; ++j) bb[j] = Bs[kk][tx * 4 + j];
#pragma unroll
            for (int i = 0; i < 4; ++i)
#pragma unroll
                for (int j = 0; j < 4; ++j)
                    acc[i][j] = fmaf(a[i], bb[j], acc[i][j]);
        }
    }
#pragma unroll
    for (int i = 0; i < 4; ++i) {
        float4 o;
        o.x = acc[i][0] + bo[n0 + tx * 4 + 0];
        o.y = acc[i][1] + bo[n0 + tx * 4 + 1];
        o.z = acc[i][2] + bo[n0 + tx * 4 + 2];
        o.w = acc[i][3] + bo[n0 + tx * 4 + 3];
        *(float4*)&Y[(size_t)(m0 + ty * 4 + i) * 1024 + n0 + tx * 4] = o;
    }
}

// ---------------------------------------------------------------------------
extern "C" void kernel_launch(void* const* d_in, const int* in_sizes, int n_in,
                              void* d_out, int out_size, void* d_ws, size_t ws_size,
                              hipStream_t stream) {
    const float* X  = (const float*)d_in[0];
    const float* Z  = (const float*)d_in[1];
    const float* Wq = (const float*)d_in[2];
    const float* bq = (const float*)d_in[3];
    const float* Wk = (const float*)d_in[4];
    const float* bk = (const float*)d_in[5];
    const float* Wv = (const float*)d_in[6];
    const float* bv = (const float*)d_in[7];
    const float* Wo = (const float*)d_in[8];
    const float* bo = (const float*)d_in[9];
    float* out = (float*)d_out;

    float* ws = (float*)d_ws;
    const size_t NQ = (size_t)NB * NH * NS * NHD;   // 4M floats per tensor
    float* Qd = ws;
    float* Kd = ws + NQ;
    float* Vd = ws + 2 * NQ;
    float* Ad = ws + 3 * NQ;                        // total 64 MB of ws

    qkv_proj<<<dim3(NB * NH * (NS / 256)), 256, 0, stream>>>(
        X, Z, Wq, bq, Wk, bk, Wv, bv, Qd, Kd, Vd);
    flash_attn<<<dim3(NS / 64, NB * NH), 256, 0, stream>>>(Qd, Kd, Vd, Ad);
    out_gemm<<<dim3(64, 16), 256, 0, stream>>>(Ad, Wo, bo, out);
}

// Round 3
// 397.435 us; speedup vs baseline: 16.9122x; 16.9122x over previous
//
#include <hip/hip_runtime.h>
#include <hip/hip_bf16.h>
#include <math.h>

#define NB   2
#define NS   2048
#define NEMB 1024
#define NH   16
#define NHD  64

typedef __attribute__((ext_vector_type(8))) short short8;
typedef __attribute__((ext_vector_type(4))) float floatx4;

static __device__ __forceinline__ ushort f2bf(float f) {
    union { float f; uint u; } x; x.f = f;
    uint r = (x.u + 0x7FFFu + ((x.u >> 16) & 1u)) >> 16;
    return (ushort)r;
}

// ---------------------------------------------------------------------------
// Kernel 1: per-head QKV projection (fp32 math, bf16 outputs).
// grid = B*H*(S/256), block = 256. W staged in LDS (pad 65).
// ---------------------------------------------------------------------------
__global__ __launch_bounds__(256) void qkv_proj(
    const float* __restrict__ X, const float* __restrict__ Z,
    const float* __restrict__ Wq, const float* __restrict__ bq,
    const float* __restrict__ Wk, const float* __restrict__ bk,
    const float* __restrict__ Wv, const float* __restrict__ bv,
    ushort* __restrict__ Q, ushort* __restrict__ K, ushort* __restrict__ V)
{
    const int SCH = NS / 256;
    int blk    = blockIdx.x;
    int schunk = blk % SCH;
    int h      = (blk / SCH) % NH;
    int b      = blk / (SCH * NH);

    __shared__ float wq[64 * 65], wk[64 * 65], wv[64 * 65];
    __shared__ float bqs[64], bks[64], bvs[64];
    __shared__ float xs[4][64], zs[4][64];

    int t = threadIdx.x;
    for (int j = t; j < 4096; j += 256) {
        int e = j >> 6, d = j & 63;
        wq[e * 65 + d] = Wq[h * 4096 + j];
        wk[e * 65 + d] = Wk[h * 4096 + j];
        wv[e * 65 + d] = Wv[h * 4096 + j];
    }
    if (t < 64) {
        bqs[t] = bq[h * 64 + t];
        bks[t] = bk[h * 64 + t];
        bvs[t] = bv[h * 64 + t];
    }
    __syncthreads();

    int rg = t >> 6;
    int e  = t & 63;
    int s0 = schunk * 256;

    for (int it = 0; it < 64; ++it) {
        int s = s0 + it * 4 + rg;
        xs[rg][e] = X[(size_t)(b * NS + s) * NEMB + h * 64 + e];
        zs[rg][e] = Z[(size_t)(b * NS + s) * NEMB + h * 64 + e];
        __syncthreads();
        float aq = bqs[e], ak = bks[e], av = bvs[e];
#pragma unroll
        for (int d = 0; d < 64; ++d) {
            float xv = xs[rg][d], zv = zs[rg][d];
            aq = fmaf(wq[e * 65 + d], xv, aq);
            ak = fmaf(wk[e * 65 + d], zv, ak);
            av = fmaf(wv[e * 65 + d], zv, av);
        }
        size_t o = ((size_t)(b * NH + h) * NS + s) * NHD + e;  // [B,H,S,HD]
        Q[o] = f2bf(aq); K[o] = f2bf(ak); V[o] = f2bf(av);
        __syncthreads();
    }
}

// ---------------------------------------------------------------------------
// Kernel 1b: V[b,h,s,d] -> Vt[b,h,d,s] (bf16), LDS tile transpose.
// grid = (S/64, B*H), block 256.
// ---------------------------------------------------------------------------
__global__ __launch_bounds__(256) void v_transpose(
    const ushort* __restrict__ V, ushort* __restrict__ Vt)
{
    int st = blockIdx.x, bh = blockIdx.y;
    const ushort* Vb = V + (size_t)bh * NS * NHD + (size_t)st * 64 * NHD;
    ushort* Tb = Vt + (size_t)bh * NHD * NS + st * 64;

    __shared__ ushort tile[64][65];   // [s][d], pad 65 to spread banks
    int t = threadIdx.x;
#pragma unroll
    for (int p = 0; p < 2; ++p) {
        int row = p * 32 + (t >> 3);
        int col = (t & 7) * 8;
        short8 v = *(const short8*)&Vb[row * 64 + col];
#pragma unroll
        for (int j = 0; j < 8; ++j) tile[row][col + j] = ((ushort*)&v)[j];
    }
    __syncthreads();
    int d = t >> 2, c4 = t & 3;
    short8 a, bpk;
#pragma unroll
    for (int j = 0; j < 8; ++j) ((ushort*)&a)[j]   = tile[c4 * 16 + j][d];
#pragma unroll
    for (int j = 0; j < 8; ++j) ((ushort*)&bpk)[j] = tile[c4 * 16 + 8 + j][d];
    *(short8*)&Tb[(size_t)d * NS + c4 * 16]     = a;
    *(short8*)&Tb[(size_t)d * NS + c4 * 16 + 8] = bpk;
}

// ---------------------------------------------------------------------------
// Kernel 2: MFMA flash attention (bf16 in, fp32 accum).
// grid = (S/64, B*H), block 256 (4 waves). Wave w owns q rows w*16..w*16+15.
// KV tiles of 64; K and Vt staged in LDS with XOR swizzle ((row&7)<<4) on the
// byte offset (row stride 128B -> 32-way conflict otherwise, G4).
// Verified layouts (m89/m91): mfma_f32_16x16x32_bf16
//   A[row=l&15][k=(l>>4)*8+j], B[k=(l>>4)*8+j][col=l&15],
//   C/D[row=(l>>4)*4+r][col=l&15].
// ---------------------------------------------------------------------------
#define SWZ(row, bytecol) (((row) * 128 + (bytecol)) ^ (((row) & 7) << 4))

__global__ __launch_bounds__(256) void flash_attn(
    const ushort* __restrict__ Q, const ushort* __restrict__ K,
    const ushort* __restrict__ Vt, float* __restrict__ A)
{
    int qt = blockIdx.x, bh = blockIdx.y;
    int h = bh & (NH - 1), b = bh >> 4;

    __shared__ __align__(16) ushort k_lds[64 * 64];   // [k][d], swizzled
    __shared__ __align__(16) ushort v_lds[64 * 64];   // [d][k], swizzled
    __shared__ __align__(16) ushort p_lds[4][16 * 72]; // per-wave P, pad 72

    int t = threadIdx.x, w = t >> 6, l = t & 63;
    int l16 = l & 15, lg = l >> 4;

    const ushort* Qb = Q + (size_t)bh * NS * NHD;
    const ushort* Kb = K + (size_t)bh * NS * NHD;
    const ushort* Vb = Vt + (size_t)bh * NHD * NS;

    int q0 = qt * 64;

    // Q fragments in registers: rows q0 + w*16 + l16, k-chunks c=0,1
    short8 qf[2];
#pragma unroll
    for (int c = 0; c < 2; ++c)
        qf[c] = *(const short8*)&Qb[(size_t)(q0 + w * 16 + l16) * 64 + c * 32 + lg * 8];

    floatx4 ob[4];            // O accum, col chunks d*16 + l16
    float m[4], ln[4];
#pragma unroll
    for (int d = 0; d < 4; ++d) ob[d] = (floatx4){0.f, 0.f, 0.f, 0.f};
#pragma unroll
    for (int r = 0; r < 4; ++r) { m[r] = -1e30f; ln[r] = 0.f; }

    for (int kt = 0; kt <= qt; ++kt) {
        __syncthreads();
        // stage K tile [64 k][64 d] and Vt tile [64 d][64 k], both swizzled
#pragma unroll
        for (int p = 0; p < 2; ++p) {
            int row = p * 32 + (t >> 3);
            int cb  = (t & 7) * 8;                     // halfword col
            short8 kv = *(const short8*)&Kb[(size_t)(kt * 64 + row) * 64 + cb];
            *(short8*)((char*)k_lds + SWZ(row, cb * 2)) = kv;
            short8 vv = *(const short8*)&Vb[(size_t)row * NS + kt * 64 + cb];
            *(short8*)((char*)v_lds + SWZ(row, cb * 2)) = vv;
        }
        __syncthreads();

        // ---- scores: S = Q K^T for 4 key-subtiles of 16 ----
        floatx4 sv[4];
#pragma unroll
        for (int st = 0; st < 4; ++st) {
            floatx4 acc = {0.f, 0.f, 0.f, 0.f};
#pragma unroll
            for (int c = 0; c < 2; ++c) {
                int row = st * 16 + l16;
                short8 kf = *(const short8*)((const char*)k_lds +
                                             SWZ(row, c * 64 + lg * 16));
                acc = __builtin_amdgcn_mfma_f32_16x16x32_bf16(qf[c], kf, acc, 0, 0, 0);
            }
            sv[st] = acc;
        }
        // scale + causal mask (diagonal tile only)
#pragma unroll
        for (int st = 0; st < 4; ++st)
#pragma unroll
            for (int r = 0; r < 4; ++r) sv[st][r] *= 0.125f;
        if (kt == qt) {
#pragma unroll
            for (int st = 0; st < 4; ++st)
#pragma unroll
                for (int r = 0; r < 4; ++r) {
                    int qq = w * 16 + lg * 4 + r;
                    int kk = st * 16 + l16;
                    if (kk > qq) sv[st][r] = -1e30f;
                }
        }
        // ---- online softmax, in-register ----
        float al[4], rs[4];
#pragma unroll
        for (int r = 0; r < 4; ++r) {
            float v = fmaxf(fmaxf(sv[0][r], sv[1][r]), fmaxf(sv[2][r], sv[3][r]));
#pragma unroll
            for (int off = 1; off < 16; off <<= 1)
                v = fmaxf(v, __shfl_xor(v, off, 64));
            float mn = fmaxf(m[r], v);
            al[r] = __expf(m[r] - mn);
            m[r] = mn;
        }
#pragma unroll
        for (int r = 0; r < 4; ++r) rs[r] = 0.f;
#pragma unroll
        for (int st = 0; st < 4; ++st)
#pragma unroll
            for (int r = 0; r < 4; ++r) {
                float p = __expf(sv[st][r] - m[r]);
                sv[st][r] = p;
                rs[r] += p;
            }
#pragma unroll
        for (int r = 0; r < 4; ++r) {
            float v = rs[r];
#pragma unroll
            for (int off = 1; off < 16; off <<= 1)
                v += __shfl_xor(v, off, 64);
            ln[r] = ln[r] * al[r] + v;
        }
#pragma unroll
        for (int d = 0; d < 4; ++d)
#pragma unroll
            for (int r = 0; r < 4; ++r) ob[d][r] *= al[r];

        // ---- P -> per-wave LDS (bf16), then PV MFMAs ----
#pragma unroll
        for (int st = 0; st < 4; ++st)
#pragma unroll
            for (int r = 0; r < 4; ++r)
                p_lds[w][(lg * 4 + r) * 72 + st * 16 + l16] = f2bf(sv[st][r]);

#pragma unroll
        for (int ks = 0; ks < 2; ++ks) {
            short8 pf = *(const short8*)((const char*)&p_lds[w][0] +
                                         (l16 * 144 + ks * 64 + lg * 16));
#pragma unroll
            for (int d = 0; d < 4; ++d) {
                int vrow = d * 16 + l16;
                short8 vf = *(const short8*)((const char*)v_lds +
                                             SWZ(vrow, ks * 64 + lg * 16));
                ob[d] = __builtin_amdgcn_mfma_f32_16x16x32_bf16(pf, vf, ob[d], 0, 0, 0);
            }
        }
    }

    // epilogue: A[b, q, h*64 + d] fp32, head-contiguous channels
#pragma unroll
    for (int d = 0; d < 4; ++d)
#pragma unroll
        for (int r = 0; r < 4; ++r) {
            int qq = q0 + w * 16 + lg * 4 + r;
            A[(size_t)(b * NS + qq) * NEMB + h * 64 + d * 16 + l16] = ob[d][r] / ln[r];
        }
}

// ---------------------------------------------------------------------------
// Kernel 3: Y = A @ Wo^T + bo (fp32).  M=4096, N=1024, K=1024.
// ---------------------------------------------------------------------------
__global__ __launch_bounds__(256) void out_gemm(
    const float* __restrict__ Aw, const float* __restrict__ Wo,
    const float* __restrict__ bo, float* __restrict__ Y)
{
    int m0 = blockIdx.x * 64;
    int n0 = blockIdx.y * 64;
    __shared__ float As[16][65];
    __shared__ float Bs[16][65];

    int t  = threadIdx.x;
    int tx = t & 15, ty = t >> 4;

    float acc[4][4];
#pragma unroll
    for (int i = 0; i < 4; ++i)
#pragma unroll
        for (int j = 0; j < 4; ++j) acc[i][j] = 0.f;

    int r  = t >> 2;
    int qq = t & 3;

    for (int k0 = 0; k0 < 1024; k0 += 16) {
        __syncthreads();
        float4 av = *(const float4*)&Aw[(size_t)(m0 + r) * 1024 + k0 + qq * 4];
        As[qq * 4 + 0][r] = av.x; As[qq * 4 + 1][r] = av.y;
        As[qq * 4 + 2][r] = av.z; As[qq * 4 + 3][r] = av.w;
        float4 bv = *(const float4*)&Wo[(size_t)(n0 + r) * 1024 + k0 + qq * 4];
        Bs[qq * 4 + 0][r] = bv.x; Bs[qq * 4 + 1][r] = bv.y;
        Bs[qq * 4 + 2][r] = bv.z; Bs[qq * 4 + 3][r] = bv.w;
        __syncthreads();
#pragma unroll
        for (int kk = 0; kk < 16; ++kk) {
            float a[4], bb[4];
#pragma unroll
            for (int i = 0; i < 4; ++i) a[i]  = As[kk][ty * 4 + i];
#pragma unroll
            for (int j = 0; j < 4; ++j) bb[j] = Bs[kk][tx * 4 + j];
#pragma unroll
            for (int i = 0; i < 4; ++i)
#pragma unroll
                for (int j = 0; j < 4; ++j)
                    acc[i][j] = fmaf(a[i], bb[j], acc[i][j]);
        }
    }
#pragma unroll
    for (int i = 0; i < 4; ++i) {
        float4 o;
        o.x = acc[i][0] + bo[n0 + tx * 4 + 0];
        o.y = acc[i][1] + bo[n0 + tx * 4 + 1];
        o.z = acc[i][2] + bo[n0 + tx * 4 + 2];
        o.w = acc[i][3] + bo[n0 + tx * 4 + 3];
        *(float4*)&Y[(size_t)(m0 + ty * 4 + i) * 1024 + n0 + tx * 4] = o;
    }
}

// ---------------------------------------------------------------------------
extern "C" void kernel_launch(void* const* d_in, const int* in_sizes, int n_in,
                              void* d_out, int out_size, void* d_ws, size_t ws_size,
                              hipStream_t stream) {
    const float* X  = (const float*)d_in[0];
    const float* Z  = (const float*)d_in[1];
    const float* Wq = (const float*)d_in[2];
    const float* bq = (const float*)d_in[3];
    const float* Wk = (const float*)d_in[4];
    const float* bk = (const float*)d_in[5];
    const float* Wv = (const float*)d_in[6];
    const float* bv = (const float*)d_in[7];
    const float* Wo = (const float*)d_in[8];
    const float* bo = (const float*)d_in[9];
    float* out = (float*)d_out;

    const size_t NQ = (size_t)NB * NH * NS * NHD;   // 4M elems
    ushort* Qd  = (ushort*)d_ws;
    ushort* Kd  = Qd + NQ;
    ushort* Vd  = Kd + NQ;
    ushort* Vtd = Vd + NQ;
    float*  Ad  = (float*)(Vtd + NQ);               // 32MB offset, 16MB fp32

    qkv_proj<<<dim3(NB * NH * (NS / 256)), 256, 0, stream>>>(
        X, Z, Wq, bq, Wk, bk, Wv, bv, Qd, Kd, Vd);
    v_transpose<<<dim3(NS / 64, NB * NH), 256, 0, stream>>>(Vd, Vtd);
    flash_attn<<<dim3(NS / 64, NB * NH), 256, 0, stream>>>(Qd, Kd, Vtd, Ad);
    out_gemm<<<dim3(64, 16), 256, 0, stream>>>(Ad, Wo, bo, out);
}

// Round 4
// 252.381 us; speedup vs baseline: 26.6323x; 1.5747x over previous
//
#include <hip/hip_runtime.h>
#include <hip/hip_bf16.h>
#include <math.h>

#define NB   2
#define NS   2048
#define NEMB 1024
#define NH   16
#define NHD  64

typedef __attribute__((ext_vector_type(8))) short short8;
typedef __attribute__((ext_vector_type(4))) float floatx4;

static __device__ __forceinline__ ushort f2bf(float f) {
    union { float f; uint u; } x; x.f = f;
    uint r = (x.u + 0x7FFFu + ((x.u >> 16) & 1u)) >> 16;
    return (ushort)r;
}

// ---------------------------------------------------------------------------
// Kernel 1: per-head QKV projection (fp32 math, bf16 outputs).
// ---------------------------------------------------------------------------
__global__ __launch_bounds__(256) void qkv_proj(
    const float* __restrict__ X, const float* __restrict__ Z,
    const float* __restrict__ Wq, const float* __restrict__ bq,
    const float* __restrict__ Wk, const float* __restrict__ bk,
    const float* __restrict__ Wv, const float* __restrict__ bv,
    ushort* __restrict__ Q, ushort* __restrict__ K, ushort* __restrict__ V)
{
    const int SCH = NS / 256;
    int blk    = blockIdx.x;
    int schunk = blk % SCH;
    int h      = (blk / SCH) % NH;
    int b      = blk / (SCH * NH);

    __shared__ float wq[64 * 65], wk[64 * 65], wv[64 * 65];
    __shared__ float bqs[64], bks[64], bvs[64];
    __shared__ float xs[4][64], zs[4][64];

    int t = threadIdx.x;
    for (int j = t; j < 4096; j += 256) {
        int e = j >> 6, d = j & 63;
        wq[e * 65 + d] = Wq[h * 4096 + j];
        wk[e * 65 + d] = Wk[h * 4096 + j];
        wv[e * 65 + d] = Wv[h * 4096 + j];
    }
    if (t < 64) {
        bqs[t] = bq[h * 64 + t];
        bks[t] = bk[h * 64 + t];
        bvs[t] = bv[h * 64 + t];
    }
    __syncthreads();

    int rg = t >> 6;
    int e  = t & 63;
    int s0 = schunk * 256;

    for (int it = 0; it < 64; ++it) {
        int s = s0 + it * 4 + rg;
        xs[rg][e] = X[(size_t)(b * NS + s) * NEMB + h * 64 + e];
        zs[rg][e] = Z[(size_t)(b * NS + s) * NEMB + h * 64 + e];
        __syncthreads();
        float aq = bqs[e], ak = bks[e], av = bvs[e];
#pragma unroll
        for (int d = 0; d < 64; ++d) {
            float xv = xs[rg][d], zv = zs[rg][d];
            aq = fmaf(wq[e * 65 + d], xv, aq);
            ak = fmaf(wk[e * 65 + d], zv, ak);
            av = fmaf(wv[e * 65 + d], zv, av);
        }
        size_t o = ((size_t)(b * NH + h) * NS + s) * NHD + e;  // [B,H,S,HD]
        Q[o] = f2bf(aq); K[o] = f2bf(ak); V[o] = f2bf(av);
        __syncthreads();
    }
}

// ---------------------------------------------------------------------------
// Kernel 1b: V[b,h,s,d] -> Vt[b,h,d,s] (bf16), LDS tile transpose.
// ---------------------------------------------------------------------------
__global__ __launch_bounds__(256) void v_transpose(
    const ushort* __restrict__ V, ushort* __restrict__ Vt)
{
    int st = blockIdx.x, bh = blockIdx.y;
    const ushort* Vb = V + (size_t)bh * NS * NHD + (size_t)st * 64 * NHD;
    ushort* Tb = Vt + (size_t)bh * NHD * NS + st * 64;

    __shared__ ushort tile[64][65];
    int t = threadIdx.x;
#pragma unroll
    for (int p = 0; p < 2; ++p) {
        int row = p * 32 + (t >> 3);
        int col = (t & 7) * 8;
        short8 v = *(const short8*)&Vb[row * 64 + col];
#pragma unroll
        for (int j = 0; j < 8; ++j) tile[row][col + j] = ((ushort*)&v)[j];
    }
    __syncthreads();
    int d = t >> 2, c4 = t & 3;
    short8 a, bpk;
#pragma unroll
    for (int j = 0; j < 8; ++j) ((ushort*)&a)[j]   = tile[c4 * 16 + j][d];
#pragma unroll
    for (int j = 0; j < 8; ++j) ((ushort*)&bpk)[j] = tile[c4 * 16 + 8 + j][d];
    *(short8*)&Tb[(size_t)d * NS + c4 * 16]     = a;
    *(short8*)&Tb[(size_t)d * NS + c4 * 16 + 8] = bpk;
}

// ---------------------------------------------------------------------------
// Kernel 1c: Wo fp32 -> bf16.  1M elems, 512 blocks x 256 thr x 8.
// ---------------------------------------------------------------------------
__global__ __launch_bounds__(256) void wo_cast(
    const float* __restrict__ Wo, ushort* __restrict__ Wob)
{
    int i = (blockIdx.x * 256 + threadIdx.x) * 8;
    float4 a = *(const float4*)&Wo[i];
    float4 b = *(const float4*)&Wo[i + 4];
    short8 o;
    ((ushort*)&o)[0] = f2bf(a.x); ((ushort*)&o)[1] = f2bf(a.y);
    ((ushort*)&o)[2] = f2bf(a.z); ((ushort*)&o)[3] = f2bf(a.w);
    ((ushort*)&o)[4] = f2bf(b.x); ((ushort*)&o)[5] = f2bf(b.y);
    ((ushort*)&o)[6] = f2bf(b.z); ((ushort*)&o)[7] = f2bf(b.w);
    *(short8*)&Wob[i] = o;
}

// ---------------------------------------------------------------------------
// Kernel 2: MFMA flash attention (bf16 in, fp32 accum, bf16 out).
// ---------------------------------------------------------------------------
#define SWZ(row, bytecol) (((row) * 128 + (bytecol)) ^ (((row) & 7) << 4))

__global__ __launch_bounds__(256) void flash_attn(
    const ushort* __restrict__ Q, const ushort* __restrict__ K,
    const ushort* __restrict__ Vt, ushort* __restrict__ A)
{
    int qt = blockIdx.x, bh = blockIdx.y;
    int h = bh & (NH - 1), b = bh >> 4;

    __shared__ __align__(16) ushort k_lds[64 * 64];
    __shared__ __align__(16) ushort v_lds[64 * 64];
    __shared__ __align__(16) ushort p_lds[4][16 * 72];

    int t = threadIdx.x, w = t >> 6, l = t & 63;
    int l16 = l & 15, lg = l >> 4;

    const ushort* Qb = Q + (size_t)bh * NS * NHD;
    const ushort* Kb = K + (size_t)bh * NS * NHD;
    const ushort* Vb = Vt + (size_t)bh * NHD * NS;

    int q0 = qt * 64;

    short8 qf[2];
#pragma unroll
    for (int c = 0; c < 2; ++c)
        qf[c] = *(const short8*)&Qb[(size_t)(q0 + w * 16 + l16) * 64 + c * 32 + lg * 8];

    floatx4 ob[4];
    float m[4], ln[4];
#pragma unroll
    for (int d = 0; d < 4; ++d) ob[d] = (floatx4){0.f, 0.f, 0.f, 0.f};
#pragma unroll
    for (int r = 0; r < 4; ++r) { m[r] = -1e30f; ln[r] = 0.f; }

    for (int kt = 0; kt <= qt; ++kt) {
        __syncthreads();
#pragma unroll
        for (int p = 0; p < 2; ++p) {
            int row = p * 32 + (t >> 3);
            int cb  = (t & 7) * 8;
            short8 kv = *(const short8*)&Kb[(size_t)(kt * 64 + row) * 64 + cb];
            *(short8*)((char*)k_lds + SWZ(row, cb * 2)) = kv;
            short8 vv = *(const short8*)&Vb[(size_t)row * NS + kt * 64 + cb];
            *(short8*)((char*)v_lds + SWZ(row, cb * 2)) = vv;
        }
        __syncthreads();

        floatx4 sv[4];
#pragma unroll
        for (int st = 0; st < 4; ++st) {
            floatx4 acc = {0.f, 0.f, 0.f, 0.f};
#pragma unroll
            for (int c = 0; c < 2; ++c) {
                int row = st * 16 + l16;
                short8 kf = *(const short8*)((const char*)k_lds +
                                             SWZ(row, c * 64 + lg * 16));
                acc = __builtin_amdgcn_mfma_f32_16x16x32_bf16(qf[c], kf, acc, 0, 0, 0);
            }
            sv[st] = acc;
        }
#pragma unroll
        for (int st = 0; st < 4; ++st)
#pragma unroll
            for (int r = 0; r < 4; ++r) sv[st][r] *= 0.125f;
        if (kt == qt) {
#pragma unroll
            for (int st = 0; st < 4; ++st)
#pragma unroll
                for (int r = 0; r < 4; ++r) {
                    int qq = w * 16 + lg * 4 + r;
                    int kk = st * 16 + l16;
                    if (kk > qq) sv[st][r] = -1e30f;
                }
        }
        float al[4], rs[4];
#pragma unroll
        for (int r = 0; r < 4; ++r) {
            float v = fmaxf(fmaxf(sv[0][r], sv[1][r]), fmaxf(sv[2][r], sv[3][r]));
#pragma unroll
            for (int off = 1; off < 16; off <<= 1)
                v = fmaxf(v, __shfl_xor(v, off, 64));
            float mn = fmaxf(m[r], v);
            al[r] = __expf(m[r] - mn);
            m[r] = mn;
        }
#pragma unroll
        for (int r = 0; r < 4; ++r) rs[r] = 0.f;
#pragma unroll
        for (int st = 0; st < 4; ++st)
#pragma unroll
            for (int r = 0; r < 4; ++r) {
                float p = __expf(sv[st][r] - m[r]);
                sv[st][r] = p;
                rs[r] += p;
            }
#pragma unroll
        for (int r = 0; r < 4; ++r) {
            float v = rs[r];
#pragma unroll
            for (int off = 1; off < 16; off <<= 1)
                v += __shfl_xor(v, off, 64);
            ln[r] = ln[r] * al[r] + v;
        }
#pragma unroll
        for (int d = 0; d < 4; ++d)
#pragma unroll
            for (int r = 0; r < 4; ++r) ob[d][r] *= al[r];

#pragma unroll
        for (int st = 0; st < 4; ++st)
#pragma unroll
            for (int r = 0; r < 4; ++r)
                p_lds[w][(lg * 4 + r) * 72 + st * 16 + l16] = f2bf(sv[st][r]);

#pragma unroll
        for (int ks = 0; ks < 2; ++ks) {
            short8 pf = *(const short8*)((const char*)&p_lds[w][0] +
                                         (l16 * 144 + ks * 64 + lg * 16));
#pragma unroll
            for (int d = 0; d < 4; ++d) {
                int vrow = d * 16 + l16;
                short8 vf = *(const short8*)((const char*)v_lds +
                                             SWZ(vrow, ks * 64 + lg * 16));
                ob[d] = __builtin_amdgcn_mfma_f32_16x16x32_bf16(pf, vf, ob[d], 0, 0, 0);
            }
        }
    }

    // epilogue: A[b, q, h*64 + d] bf16, head-contiguous channels
#pragma unroll
    for (int d = 0; d < 4; ++d)
#pragma unroll
        for (int r = 0; r < 4; ++r) {
            int qq = q0 + w * 16 + lg * 4 + r;
            A[(size_t)(b * NS + qq) * NEMB + h * 64 + d * 16 + l16] =
                f2bf(ob[d][r] / ln[r]);
        }
}

// ---------------------------------------------------------------------------
// Kernel 3: Y = A @ Wo^T + bo via bf16 MFMA, fp32 accum.
// M=4096, N=1024, K=1024. 128x128 tile, BK=64, 4 waves (2x2), 4x4 frags.
// Both operands row-major over K -> identical staging/swizzle as flash_attn.
// grid = (32, 8) = 256 blocks = 1/CU.
// ---------------------------------------------------------------------------
__global__ __launch_bounds__(256) void out_gemm_mfma(
    const ushort* __restrict__ Aq, const ushort* __restrict__ Wob,
    const float* __restrict__ bo, float* __restrict__ Y)
{
    int m0 = blockIdx.x * 128;
    int n0 = blockIdx.y * 128;

    __shared__ __align__(16) ushort As[128 * 64];  // [m][k], swizzled
    __shared__ __align__(16) ushort Bs[128 * 64];  // [n][k], swizzled

    int t = threadIdx.x, w = t >> 6, l = t & 63;
    int l16 = l & 15, lg = l >> 4;
    int wr = w >> 1, wc = w & 1;     // wave quadrant: rows wr*64, cols wc*64

    floatx4 acc[4][4];
#pragma unroll
    for (int i = 0; i < 4; ++i)
#pragma unroll
        for (int j = 0; j < 4; ++j) acc[i][j] = (floatx4){0.f, 0.f, 0.f, 0.f};

    for (int kt = 0; kt < 16; ++kt) {
        __syncthreads();
        // stage 128x64 A and B tiles: 1024 16B-chunks each over 256 threads
#pragma unroll
        for (int i = 0; i < 4; ++i) {
            int chunk = i * 256 + t;          // 0..1023
            int row   = chunk >> 3;           // 0..127 (8 chunks per 128B row)
            int c16   = chunk & 7;
            short8 av = *(const short8*)&Aq[(size_t)(m0 + row) * 1024 + kt * 64 + c16 * 8];
            *(short8*)((char*)As + SWZ(row, c16 * 16)) = av;
            short8 bv = *(const short8*)&Wob[(size_t)(n0 + row) * 1024 + kt * 64 + c16 * 8];
            *(short8*)((char*)Bs + SWZ(row, c16 * 16)) = bv;
        }
        __syncthreads();
#pragma unroll
        for (int kc = 0; kc < 2; ++kc) {
            short8 af[4], bf[4];
#pragma unroll
            for (int i = 0; i < 4; ++i) {
                int arow = wr * 64 + i * 16 + l16;
                af[i] = *(const short8*)((const char*)As + SWZ(arow, kc * 64 + lg * 16));
                int brow = wc * 64 + i * 16 + l16;
                bf[i] = *(const short8*)((const char*)Bs + SWZ(brow, kc * 64 + lg * 16));
            }
#pragma unroll
            for (int i = 0; i < 4; ++i)
#pragma unroll
                for (int j = 0; j < 4; ++j)
                    acc[i][j] = __builtin_amdgcn_mfma_f32_16x16x32_bf16(
                        af[i], bf[j], acc[i][j], 0, 0, 0);
        }
    }
    // epilogue: C/D layout row=(l>>4)*4+r, col=l&15
#pragma unroll
    for (int i = 0; i < 4; ++i)
#pragma unroll
        for (int j = 0; j < 4; ++j) {
            int nn = n0 + wc * 64 + j * 16 + l16;
            float bb = bo[nn];
#pragma unroll
            for (int r = 0; r < 4; ++r) {
                int mm = m0 + wr * 64 + i * 16 + lg * 4 + r;
                Y[(size_t)mm * 1024 + nn] = acc[i][j][r] + bb;
            }
        }
}

// ---------------------------------------------------------------------------
extern "C" void kernel_launch(void* const* d_in, const int* in_sizes, int n_in,
                              void* d_out, int out_size, void* d_ws, size_t ws_size,
                              hipStream_t stream) {
    const float* X  = (const float*)d_in[0];
    const float* Z  = (const float*)d_in[1];
    const float* Wq = (const float*)d_in[2];
    const float* bq = (const float*)d_in[3];
    const float* Wk = (const float*)d_in[4];
    const float* bk = (const float*)d_in[5];
    const float* Wv = (const float*)d_in[6];
    const float* bv = (const float*)d_in[7];
    const float* Wo = (const float*)d_in[8];
    const float* bo = (const float*)d_in[9];
    float* out = (float*)d_out;

    const size_t NQ = (size_t)NB * NH * NS * NHD;   // 4M elems
    ushort* Qd  = (ushort*)d_ws;
    ushort* Kd  = Qd + NQ;
    ushort* Vd  = Kd + NQ;
    ushort* Vtd = Vd + NQ;
    ushort* Ad  = Vtd + NQ;                         // bf16 attention output
    ushort* Wob = Ad + NQ;                          // bf16 Wo (1M elems)

    qkv_proj<<<dim3(NB * NH * (NS / 256)), 256, 0, stream>>>(
        X, Z, Wq, bq, Wk, bk, Wv, bv, Qd, Kd, Vd);
    wo_cast<<<dim3(512), 256, 0, stream>>>(Wo, Wob);
    v_transpose<<<dim3(NS / 64, NB * NH), 256, 0, stream>>>(Vd, Vtd);
    flash_attn<<<dim3(NS / 64, NB * NH), 256, 0, stream>>>(Qd, Kd, Vtd, Ad);
    out_gemm_mfma<<<dim3(32, 8), 256, 0, stream>>>(Ad, Wob, bo, out);
}

// Round 5
// 145.157 us; speedup vs baseline: 46.3051x; 1.7387x over previous
//
#include <hip/hip_runtime.h>
#include <hip/hip_bf16.h>
#include <math.h>

#define NB   2
#define NS   2048
#define NEMB 1024
#define NH   16
#define NHD  64

typedef __attribute__((ext_vector_type(8))) short short8;
typedef __attribute__((ext_vector_type(4))) float floatx4;

static __device__ __forceinline__ ushort f2bf(float f) {
    union { float f; uint u; } x; x.f = f;
    uint r = (x.u + 0x7FFFu + ((x.u >> 16) & 1u)) >> 16;
    return (ushort)r;
}
static __device__ __forceinline__ float bf2f(ushort u) {
    union { uint u; float f; } x; x.u = ((uint)u) << 16;
    return x.f;
}

#define SWZ(row, bytecol) (((row) * 128 + (bytecol)) ^ (((row) & 7) << 4))

// ---------------------------------------------------------------------------
// Kernel 1: fused QKV projection via MFMA (fp32 in, bf16 out), emits Q, K and
// TRANSPOSED V (Vt[b,h,d,s]) directly. grid = (S/128, B*H), block 256.
// Per block: stage X/Z tiles [128s x 64d] + Wq/Wk/Wv [64e x 64d] as bf16,
// 3 GEMMs (M=128,N=64,K=64), wave w owns rows w*32..w*32+31.
// ---------------------------------------------------------------------------
__global__ __launch_bounds__(256) void qkv_mfma(
    const float* __restrict__ X, const float* __restrict__ Z,
    const float* __restrict__ Wq, const float* __restrict__ bq,
    const float* __restrict__ Wk, const float* __restrict__ bk,
    const float* __restrict__ Wv, const float* __restrict__ bv,
    ushort* __restrict__ Q, ushort* __restrict__ K, ushort* __restrict__ Vt)
{
    int st = blockIdx.x, bh = blockIdx.y;
    int h = bh & (NH - 1), b = bh >> 4;
    int s0 = st * 128;

    // staging region: rows of 128B, SWZ layout (16KB used of each buffer);
    // repack region (after compute): ushort stride 72 (144B rows, 18.4KB)
    __shared__ __align__(16) ushort xs[128 * 72];
    __shared__ __align__(16) ushort zs[128 * 72];
    __shared__ __align__(16) ushort wqs[64 * 64], wks[64 * 64], wvs[64 * 64];

    int t = threadIdx.x, w = t >> 6, l = t & 63;
    int l16 = l & 15, lg = l >> 4;

    // ---- stage X, Z (fp32 -> bf16) ----
#pragma unroll
    for (int c = 0; c < 4; ++c) {
        int chunk = c * 256 + t;            // 0..1023
        int row   = chunk >> 3;             // 0..127
        int c8    = chunk & 7;              // 8-d group
        const float* px = &X[(size_t)(b * NS + s0 + row) * NEMB + h * 64 + c8 * 8];
        const float* pz = &Z[(size_t)(b * NS + s0 + row) * NEMB + h * 64 + c8 * 8];
        float4 a0 = *(const float4*)px, a1 = *(const float4*)(px + 4);
        float4 z0 = *(const float4*)pz, z1 = *(const float4*)(pz + 4);
        short8 xv, zv;
        ((ushort*)&xv)[0] = f2bf(a0.x); ((ushort*)&xv)[1] = f2bf(a0.y);
        ((ushort*)&xv)[2] = f2bf(a0.z); ((ushort*)&xv)[3] = f2bf(a0.w);
        ((ushort*)&xv)[4] = f2bf(a1.x); ((ushort*)&xv)[5] = f2bf(a1.y);
        ((ushort*)&xv)[6] = f2bf(a1.z); ((ushort*)&xv)[7] = f2bf(a1.w);
        ((ushort*)&zv)[0] = f2bf(z0.x); ((ushort*)&zv)[1] = f2bf(z0.y);
        ((ushort*)&zv)[2] = f2bf(z0.z); ((ushort*)&zv)[3] = f2bf(z0.w);
        ((ushort*)&zv)[4] = f2bf(z1.x); ((ushort*)&zv)[5] = f2bf(z1.y);
        ((ushort*)&zv)[6] = f2bf(z1.z); ((ushort*)&zv)[7] = f2bf(z1.w);
        *(short8*)((char*)xs + SWZ(row, c8 * 16)) = xv;
        *(short8*)((char*)zs + SWZ(row, c8 * 16)) = zv;
    }
    // ---- stage Wq/Wk/Wv (fp32 -> bf16) ----
#pragma unroll
    for (int c = 0; c < 2; ++c) {
        int chunk = c * 256 + t;            // 0..511
        int row   = chunk >> 3;             // e: 0..63
        int c8    = chunk & 7;
        const float* pq = &Wq[(size_t)h * 4096 + row * 64 + c8 * 8];
        const float* pk = &Wk[(size_t)h * 4096 + row * 64 + c8 * 8];
        const float* pv = &Wv[(size_t)h * 4096 + row * 64 + c8 * 8];
        float4 q0 = *(const float4*)pq, q1 = *(const float4*)(pq + 4);
        float4 k0 = *(const float4*)pk, k1 = *(const float4*)(pk + 4);
        float4 v0 = *(const float4*)pv, v1 = *(const float4*)(pv + 4);
        short8 qv, kv, vv;
#pragma unroll
        for (int j = 0; j < 4; ++j) {
            ((ushort*)&qv)[j]     = f2bf(((const float*)&q0)[j]);
            ((ushort*)&qv)[j + 4] = f2bf(((const float*)&q1)[j]);
            ((ushort*)&kv)[j]     = f2bf(((const float*)&k0)[j]);
            ((ushort*)&kv)[j + 4] = f2bf(((const float*)&k1)[j]);
            ((ushort*)&vv)[j]     = f2bf(((const float*)&v0)[j]);
            ((ushort*)&vv)[j + 4] = f2bf(((const float*)&v1)[j]);
        }
        *(short8*)((char*)wqs + SWZ(row, c8 * 16)) = qv;
        *(short8*)((char*)wks + SWZ(row, c8 * 16)) = kv;
        *(short8*)((char*)wvs + SWZ(row, c8 * 16)) = vv;
    }
    __syncthreads();

    floatx4 aq[2][4], ak[2][4], av[2][4];
#pragma unroll
    for (int i = 0; i < 2; ++i)
#pragma unroll
        for (int j = 0; j < 4; ++j) {
            aq[i][j] = (floatx4){0.f, 0.f, 0.f, 0.f};
            ak[i][j] = (floatx4){0.f, 0.f, 0.f, 0.f};
            av[i][j] = (floatx4){0.f, 0.f, 0.f, 0.f};
        }

#pragma unroll
    for (int kc = 0; kc < 2; ++kc) {
        short8 xa[2], za[2];
#pragma unroll
        for (int i = 0; i < 2; ++i) {
            int row = w * 32 + i * 16 + l16;
            xa[i] = *(const short8*)((const char*)xs + SWZ(row, kc * 64 + lg * 16));
            za[i] = *(const short8*)((const char*)zs + SWZ(row, kc * 64 + lg * 16));
        }
#pragma unroll
        for (int j = 0; j < 4; ++j) {
            int row = j * 16 + l16;
            short8 wqf = *(const short8*)((const char*)wqs + SWZ(row, kc * 64 + lg * 16));
            short8 wkf = *(const short8*)((const char*)wks + SWZ(row, kc * 64 + lg * 16));
            short8 wvf = *(const short8*)((const char*)wvs + SWZ(row, kc * 64 + lg * 16));
#pragma unroll
            for (int i = 0; i < 2; ++i) {
                aq[i][j] = __builtin_amdgcn_mfma_f32_16x16x32_bf16(xa[i], wqf, aq[i][j], 0, 0, 0);
                ak[i][j] = __builtin_amdgcn_mfma_f32_16x16x32_bf16(za[i], wkf, ak[i][j], 0, 0, 0);
                av[i][j] = __builtin_amdgcn_mfma_f32_16x16x32_bf16(za[i], wvf, av[i][j], 0, 0, 0);
            }
        }
    }

    float bqv[4], bkv[4], bvv[4];
#pragma unroll
    for (int j = 0; j < 4; ++j) {
        bqv[j] = bq[h * 64 + j * 16 + l16];
        bkv[j] = bk[h * 64 + j * 16 + l16];
        bvv[j] = bv[h * 64 + j * 16 + l16];
    }

    // ---- Vt direct scatter: lane holds rows s=base..base+3 at fixed d ----
#pragma unroll
    for (int i = 0; i < 2; ++i)
#pragma unroll
        for (int j = 0; j < 4; ++j) {
            int d = j * 16 + l16;
            int s = s0 + w * 32 + i * 16 + lg * 4;
            ushort4 pv;
            pv.x = f2bf(av[i][j][0] + bvv[j]);
            pv.y = f2bf(av[i][j][1] + bvv[j]);
            pv.z = f2bf(av[i][j][2] + bvv[j]);
            pv.w = f2bf(av[i][j][3] + bvv[j]);
            *(ushort4*)&Vt[((size_t)bh * NHD + d) * NS + s] = pv;
        }

    // ---- Q,K repack through LDS (stride 72 ushort = 144B rows) -> coalesced ----
    __syncthreads();   // all MFMA LDS reads done; reuse xs/zs
#pragma unroll
    for (int i = 0; i < 2; ++i)
#pragma unroll
        for (int j = 0; j < 4; ++j)
#pragma unroll
            for (int r = 0; r < 4; ++r) {
                int s = w * 32 + i * 16 + lg * 4 + r;
                xs[s * 72 + j * 16 + l16] = f2bf(aq[i][j][r] + bqv[j]);
                zs[s * 72 + j * 16 + l16] = f2bf(ak[i][j][r] + bkv[j]);
            }
    __syncthreads();
#pragma unroll
    for (int c = 0; c < 4; ++c) {
        int chunk = c * 256 + t;
        int row   = chunk >> 3;
        int c8    = chunk & 7;
        short8 qv = *(const short8*)&xs[row * 72 + c8 * 8];
        short8 kv = *(const short8*)&zs[row * 72 + c8 * 8];
        *(short8*)&Q[((size_t)bh * NS + s0 + row) * 64 + c8 * 8] = qv;
        *(short8*)&K[((size_t)bh * NS + s0 + row) * 64 + c8 * 8] = kv;
    }
}

// ---------------------------------------------------------------------------
// Kernel 1c: Wo fp32 -> bf16.
// ---------------------------------------------------------------------------
__global__ __launch_bounds__(256) void wo_cast(
    const float* __restrict__ Wo, ushort* __restrict__ Wob)
{
    int i = (blockIdx.x * 256 + threadIdx.x) * 8;
    float4 a = *(const float4*)&Wo[i];
    float4 b = *(const float4*)&Wo[i + 4];
    short8 o;
    ((ushort*)&o)[0] = f2bf(a.x); ((ushort*)&o)[1] = f2bf(a.y);
    ((ushort*)&o)[2] = f2bf(a.z); ((ushort*)&o)[3] = f2bf(a.w);
    ((ushort*)&o)[4] = f2bf(b.x); ((ushort*)&o)[5] = f2bf(b.y);
    ((ushort*)&o)[6] = f2bf(b.z); ((ushort*)&o)[7] = f2bf(b.w);
    *(short8*)&Wob[i] = o;
}

// ---------------------------------------------------------------------------
// Kernel 2: MFMA flash attention (bf16 in, fp32 accum, bf16 out).
// Reversed-qt dispatch (heavy blocks first) + register prefetch of next K/V
// tile so HBM latency hides under compute (T14). Q pre-scaled by 0.125.
// ---------------------------------------------------------------------------
__global__ __launch_bounds__(256) void flash_attn(
    const ushort* __restrict__ Q, const ushort* __restrict__ K,
    const ushort* __restrict__ Vt, ushort* __restrict__ A)
{
    int qt = (gridDim.x - 1) - blockIdx.x;   // heavy (large qt) first
    int bh = blockIdx.y;
    int h = bh & (NH - 1), b = bh >> 4;

    __shared__ __align__(16) ushort k_lds[64 * 64];
    __shared__ __align__(16) ushort v_lds[64 * 64];
    __shared__ __align__(16) ushort p_lds[4][16 * 72];

    int t = threadIdx.x, w = t >> 6, l = t & 63;
    int l16 = l & 15, lg = l >> 4;

    const ushort* Qb = Q + (size_t)bh * NS * NHD;
    const ushort* Kb = K + (size_t)bh * NS * NHD;
    const ushort* Vb = Vt + (size_t)bh * NHD * NS;

    int q0 = qt * 64;

    // Q fragments, pre-scaled by 1/sqrt(64)=0.125 (exact in bf16)
    short8 qf[2];
#pragma unroll
    for (int c = 0; c < 2; ++c) {
        short8 raw = *(const short8*)&Qb[(size_t)(q0 + w * 16 + l16) * 64 + c * 32 + lg * 8];
#pragma unroll
        for (int j = 0; j < 8; ++j)
            ((ushort*)&qf[c])[j] = f2bf(bf2f(((ushort*)&raw)[j]) * 0.125f);
    }

    floatx4 ob[4];
    float m[4], ln[4];
#pragma unroll
    for (int d = 0; d < 4; ++d) ob[d] = (floatx4){0.f, 0.f, 0.f, 0.f};
#pragma unroll
    for (int r = 0; r < 4; ++r) { m[r] = -1e30f; ln[r] = 0.f; }

    int rrow = t >> 3, rcb = (t & 7) * 8;   // staging chunk assignment
    short8 kpre[2], vpre[2];
#pragma unroll
    for (int p = 0; p < 2; ++p) {
        kpre[p] = *(const short8*)&Kb[(size_t)(p * 32 + rrow) * 64 + rcb];
        vpre[p] = *(const short8*)&Vb[(size_t)(p * 32 + rrow) * NS + rcb];
    }

    for (int kt = 0; kt <= qt; ++kt) {
        if (kt) __syncthreads();             // all waves done reading prev tile
#pragma unroll
        for (int p = 0; p < 2; ++p) {
            *(short8*)((char*)k_lds + SWZ(p * 32 + rrow, rcb * 2)) = kpre[p];
            *(short8*)((char*)v_lds + SWZ(p * 32 + rrow, rcb * 2)) = vpre[p];
        }
        __syncthreads();
        if (kt < qt) {                        // issue next-tile loads early
#pragma unroll
            for (int p = 0; p < 2; ++p) {
                kpre[p] = *(const short8*)&Kb[(size_t)((kt + 1) * 64 + p * 32 + rrow) * 64 + rcb];
                vpre[p] = *(const short8*)&Vb[(size_t)(p * 32 + rrow) * NS + (kt + 1) * 64 + rcb];
            }
        }

        floatx4 sv[4];
#pragma unroll
        for (int stt = 0; stt < 4; ++stt) {
            floatx4 acc = {0.f, 0.f, 0.f, 0.f};
#pragma unroll
            for (int c = 0; c < 2; ++c) {
                int row = stt * 16 + l16;
                short8 kf = *(const short8*)((const char*)k_lds +
                                             SWZ(row, c * 64 + lg * 16));
                acc = __builtin_amdgcn_mfma_f32_16x16x32_bf16(qf[c], kf, acc, 0, 0, 0);
            }
            sv[stt] = acc;
        }
        if (kt == qt) {
#pragma unroll
            for (int stt = 0; stt < 4; ++stt)
#pragma unroll
                for (int r = 0; r < 4; ++r) {
                    int qq = w * 16 + lg * 4 + r;
                    int kk = stt * 16 + l16;
                    if (kk > qq) sv[stt][r] = -1e30f;
                }
        }
        float al[4], rs[4];
#pragma unroll
        for (int r = 0; r < 4; ++r) {
            float v = fmaxf(fmaxf(sv[0][r], sv[1][r]), fmaxf(sv[2][r], sv[3][r]));
#pragma unroll
            for (int off = 1; off < 16; off <<= 1)
                v = fmaxf(v, __shfl_xor(v, off, 64));
            float mn = fmaxf(m[r], v);
            al[r] = __expf(m[r] - mn);
            m[r] = mn;
        }
#pragma unroll
        for (int r = 0; r < 4; ++r) rs[r] = 0.f;
#pragma unroll
        for (int stt = 0; stt < 4; ++stt)
#pragma unroll
            for (int r = 0; r < 4; ++r) {
                float p = __expf(sv[stt][r] - m[r]);
                sv[stt][r] = p;
                rs[r] += p;
            }
#pragma unroll
        for (int r = 0; r < 4; ++r) {
            float v = rs[r];
#pragma unroll
            for (int off = 1; off < 16; off <<= 1)
                v += __shfl_xor(v, off, 64);
            ln[r] = ln[r] * al[r] + v;
        }
#pragma unroll
        for (int d = 0; d < 4; ++d)
#pragma unroll
            for (int r = 0; r < 4; ++r) ob[d][r] *= al[r];

#pragma unroll
        for (int stt = 0; stt < 4; ++stt)
#pragma unroll
            for (int r = 0; r < 4; ++r)
                p_lds[w][(lg * 4 + r) * 72 + stt * 16 + l16] = f2bf(sv[stt][r]);

#pragma unroll
        for (int ks = 0; ks < 2; ++ks) {
            short8 pf = *(const short8*)((const char*)&p_lds[w][0] +
                                         (l16 * 144 + ks * 64 + lg * 16));
#pragma unroll
            for (int d = 0; d < 4; ++d) {
                int vrow = d * 16 + l16;
                short8 vf = *(const short8*)((const char*)v_lds +
                                             SWZ(vrow, ks * 64 + lg * 16));
                ob[d] = __builtin_amdgcn_mfma_f32_16x16x32_bf16(pf, vf, ob[d], 0, 0, 0);
            }
        }
    }

#pragma unroll
    for (int d = 0; d < 4; ++d)
#pragma unroll
        for (int r = 0; r < 4; ++r) {
            int qq = q0 + w * 16 + lg * 4 + r;
            A[(size_t)(b * NS + qq) * NEMB + h * 64 + d * 16 + l16] =
                f2bf(ob[d][r] / ln[r]);
        }
}

// ---------------------------------------------------------------------------
// Kernel 3: Y = A @ Wo^T + bo via bf16 MFMA, fp32 accum. (unchanged)
// ---------------------------------------------------------------------------
__global__ __launch_bounds__(256) void out_gemm_mfma(
    const ushort* __restrict__ Aq, const ushort* __restrict__ Wob,
    const float* __restrict__ bo, float* __restrict__ Y)
{
    int m0 = blockIdx.x * 128;
    int n0 = blockIdx.y * 128;

    __shared__ __align__(16) ushort As[128 * 64];
    __shared__ __align__(16) ushort Bs[128 * 64];

    int t = threadIdx.x, w = t >> 6, l = t & 63;
    int l16 = l & 15, lg = l >> 4;
    int wr = w >> 1, wc = w & 1;

    floatx4 acc[4][4];
#pragma unroll
    for (int i = 0; i < 4; ++i)
#pragma unroll
        for (int j = 0; j < 4; ++j) acc[i][j] = (floatx4){0.f, 0.f, 0.f, 0.f};

    for (int kt = 0; kt < 16; ++kt) {
        __syncthreads();
#pragma unroll
        for (int i = 0; i < 4; ++i) {
            int chunk = i * 256 + t;
            int row   = chunk >> 3;
            int c16   = chunk & 7;
            short8 av = *(const short8*)&Aq[(size_t)(m0 + row) * 1024 + kt * 64 + c16 * 8];
            *(short8*)((char*)As + SWZ(row, c16 * 16)) = av;
            short8 bv = *(const short8*)&Wob[(size_t)(n0 + row) * 1024 + kt * 64 + c16 * 8];
            *(short8*)((char*)Bs + SWZ(row, c16 * 16)) = bv;
        }
        __syncthreads();
#pragma unroll
        for (int kc = 0; kc < 2; ++kc) {
            short8 af[4], bf[4];
#pragma unroll
            for (int i = 0; i < 4; ++i) {
                int arow = wr * 64 + i * 16 + l16;
                af[i] = *(const short8*)((const char*)As + SWZ(arow, kc * 64 + lg * 16));
                int brow = wc * 64 + i * 16 + l16;
                bf[i] = *(const short8*)((const char*)Bs + SWZ(brow, kc * 64 + lg * 16));
            }
#pragma unroll
            for (int i = 0; i < 4; ++i)
#pragma unroll
                for (int j = 0; j < 4; ++j)
                    acc[i][j] = __builtin_amdgcn_mfma_f32_16x16x32_bf16(
                        af[i], bf[j], acc[i][j], 0, 0, 0);
        }
    }
#pragma unroll
    for (int i = 0; i < 4; ++i)
#pragma unroll
        for (int j = 0; j < 4; ++j) {
            int nn = n0 + wc * 64 + j * 16 + l16;
            float bb = bo[nn];
#pragma unroll
            for (int r = 0; r < 4; ++r) {
                int mm = m0 + wr * 64 + i * 16 + lg * 4 + r;
                Y[(size_t)mm * 1024 + nn] = acc[i][j][r] + bb;
            }
        }
}

// ---------------------------------------------------------------------------
extern "C" void kernel_launch(void* const* d_in, const int* in_sizes, int n_in,
                              void* d_out, int out_size, void* d_ws, size_t ws_size,
                              hipStream_t stream) {
    const float* X  = (const float*)d_in[0];
    const float* Z  = (const float*)d_in[1];
    const float* Wq = (const float*)d_in[2];
    const float* bq = (const float*)d_in[3];
    const float* Wk = (const float*)d_in[4];
    const float* bk = (const float*)d_in[5];
    const float* Wv = (const float*)d_in[6];
    const float* bv = (const float*)d_in[7];
    const float* Wo = (const float*)d_in[8];
    const float* bo = (const float*)d_in[9];
    float* out = (float*)d_out;

    const size_t NQ = (size_t)NB * NH * NS * NHD;   // 4M elems
    ushort* Qd  = (ushort*)d_ws;
    ushort* Kd  = Qd + NQ;
    ushort* Vtd = Kd + NQ;
    ushort* Ad  = Vtd + NQ;
    ushort* Wob = Ad + NQ;

    qkv_mfma<<<dim3(NS / 128, NB * NH), 256, 0, stream>>>(
        X, Z, Wq, bq, Wk, bk, Wv, bv, Qd, Kd, Vtd);
    wo_cast<<<dim3(512), 256, 0, stream>>>(Wo, Wob);
    flash_attn<<<dim3(NS / 64, NB * NH), 256, 0, stream>>>(Qd, Kd, Vtd, Ad);
    out_gemm_mfma<<<dim3(32, 8), 256, 0, stream>>>(Ad, Wob, bo, out);
}

// Round 6
// 122.043 us; speedup vs baseline: 55.0749x; 1.1894x over previous
//
#include <hip/hip_runtime.h>
#include <hip/hip_bf16.h>
#include <math.h>

#define NB   2
#define NS   2048
#define NEMB 1024
#define NH   16
#define NHD  64

typedef __attribute__((ext_vector_type(8))) short short8;
typedef __attribute__((ext_vector_type(4))) float floatx4;

static __device__ __forceinline__ ushort f2bf(float f) {
    union { float f; uint u; } x; x.f = f;
    uint r = (x.u + 0x7FFFu + ((x.u >> 16) & 1u)) >> 16;
    return (ushort)r;
}
static __device__ __forceinline__ float bf2f(ushort u) {
    union { uint u; float f; } x; x.u = ((uint)u) << 16;
    return x.f;
}

#define SWZ(row, bytecol) (((row) * 128 + (bytecol)) ^ (((row) & 7) << 4))

// ---------------------------------------------------------------------------
// Kernel 1: fused QKV projection via MFMA (fp32 in, bf16 out), emits Q, K and
// TRANSPOSED V (Vt[b,h,d,s]) directly. grid = (S/128, B*H), block 256.
// ---------------------------------------------------------------------------
__global__ __launch_bounds__(256) void qkv_mfma(
    const float* __restrict__ X, const float* __restrict__ Z,
    const float* __restrict__ Wq, const float* __restrict__ bq,
    const float* __restrict__ Wk, const float* __restrict__ bk,
    const float* __restrict__ Wv, const float* __restrict__ bv,
    ushort* __restrict__ Q, ushort* __restrict__ K, ushort* __restrict__ Vt)
{
    int st = blockIdx.x, bh = blockIdx.y;
    int h = bh & (NH - 1), b = bh >> 4;
    int s0 = st * 128;

    __shared__ __align__(16) ushort xs[128 * 72];
    __shared__ __align__(16) ushort zs[128 * 72];
    __shared__ __align__(16) ushort wqs[64 * 64], wks[64 * 64], wvs[64 * 64];

    int t = threadIdx.x, w = t >> 6, l = t & 63;
    int l16 = l & 15, lg = l >> 4;

#pragma unroll
    for (int c = 0; c < 4; ++c) {
        int chunk = c * 256 + t;
        int row   = chunk >> 3;
        int c8    = chunk & 7;
        const float* px = &X[(size_t)(b * NS + s0 + row) * NEMB + h * 64 + c8 * 8];
        const float* pz = &Z[(size_t)(b * NS + s0 + row) * NEMB + h * 64 + c8 * 8];
        float4 a0 = *(const float4*)px, a1 = *(const float4*)(px + 4);
        float4 z0 = *(const float4*)pz, z1 = *(const float4*)(pz + 4);
        short8 xv, zv;
        ((ushort*)&xv)[0] = f2bf(a0.x); ((ushort*)&xv)[1] = f2bf(a0.y);
        ((ushort*)&xv)[2] = f2bf(a0.z); ((ushort*)&xv)[3] = f2bf(a0.w);
        ((ushort*)&xv)[4] = f2bf(a1.x); ((ushort*)&xv)[5] = f2bf(a1.y);
        ((ushort*)&xv)[6] = f2bf(a1.z); ((ushort*)&xv)[7] = f2bf(a1.w);
        ((ushort*)&zv)[0] = f2bf(z0.x); ((ushort*)&zv)[1] = f2bf(z0.y);
        ((ushort*)&zv)[2] = f2bf(z0.z); ((ushort*)&zv)[3] = f2bf(z0.w);
        ((ushort*)&zv)[4] = f2bf(z1.x); ((ushort*)&zv)[5] = f2bf(z1.y);
        ((ushort*)&zv)[6] = f2bf(z1.z); ((ushort*)&zv)[7] = f2bf(z1.w);
        *(short8*)((char*)xs + SWZ(row, c8 * 16)) = xv;
        *(short8*)((char*)zs + SWZ(row, c8 * 16)) = zv;
    }
#pragma unroll
    for (int c = 0; c < 2; ++c) {
        int chunk = c * 256 + t;
        int row   = chunk >> 3;
        int c8    = chunk & 7;
        const float* pq = &Wq[(size_t)h * 4096 + row * 64 + c8 * 8];
        const float* pk = &Wk[(size_t)h * 4096 + row * 64 + c8 * 8];
        const float* pv = &Wv[(size_t)h * 4096 + row * 64 + c8 * 8];
        float4 q0 = *(const float4*)pq, q1 = *(const float4*)(pq + 4);
        float4 k0 = *(const float4*)pk, k1 = *(const float4*)(pk + 4);
        float4 v0 = *(const float4*)pv, v1 = *(const float4*)(pv + 4);
        short8 qv, kv, vv;
#pragma unroll
        for (int j = 0; j < 4; ++j) {
            ((ushort*)&qv)[j]     = f2bf(((const float*)&q0)[j]);
            ((ushort*)&qv)[j + 4] = f2bf(((const float*)&q1)[j]);
            ((ushort*)&kv)[j]     = f2bf(((const float*)&k0)[j]);
            ((ushort*)&kv)[j + 4] = f2bf(((const float*)&k1)[j]);
            ((ushort*)&vv)[j]     = f2bf(((const float*)&v0)[j]);
            ((ushort*)&vv)[j + 4] = f2bf(((const float*)&v1)[j]);
        }
        *(short8*)((char*)wqs + SWZ(row, c8 * 16)) = qv;
        *(short8*)((char*)wks + SWZ(row, c8 * 16)) = kv;
        *(short8*)((char*)wvs + SWZ(row, c8 * 16)) = vv;
    }
    __syncthreads();

    floatx4 aq[2][4], ak[2][4], av[2][4];
#pragma unroll
    for (int i = 0; i < 2; ++i)
#pragma unroll
        for (int j = 0; j < 4; ++j) {
            aq[i][j] = (floatx4){0.f, 0.f, 0.f, 0.f};
            ak[i][j] = (floatx4){0.f, 0.f, 0.f, 0.f};
            av[i][j] = (floatx4){0.f, 0.f, 0.f, 0.f};
        }

#pragma unroll
    for (int kc = 0; kc < 2; ++kc) {
        short8 xa[2], za[2];
#pragma unroll
        for (int i = 0; i < 2; ++i) {
            int row = w * 32 + i * 16 + l16;
            xa[i] = *(const short8*)((const char*)xs + SWZ(row, kc * 64 + lg * 16));
            za[i] = *(const short8*)((const char*)zs + SWZ(row, kc * 64 + lg * 16));
        }
#pragma unroll
        for (int j = 0; j < 4; ++j) {
            int row = j * 16 + l16;
            short8 wqf = *(const short8*)((const char*)wqs + SWZ(row, kc * 64 + lg * 16));
            short8 wkf = *(const short8*)((const char*)wks + SWZ(row, kc * 64 + lg * 16));
            short8 wvf = *(const short8*)((const char*)wvs + SWZ(row, kc * 64 + lg * 16));
#pragma unroll
            for (int i = 0; i < 2; ++i) {
                aq[i][j] = __builtin_amdgcn_mfma_f32_16x16x32_bf16(xa[i], wqf, aq[i][j], 0, 0, 0);
                ak[i][j] = __builtin_amdgcn_mfma_f32_16x16x32_bf16(za[i], wkf, ak[i][j], 0, 0, 0);
                av[i][j] = __builtin_amdgcn_mfma_f32_16x16x32_bf16(za[i], wvf, av[i][j], 0, 0, 0);
            }
        }
    }

    float bqv[4], bkv[4], bvv[4];
#pragma unroll
    for (int j = 0; j < 4; ++j) {
        bqv[j] = bq[h * 64 + j * 16 + l16];
        bkv[j] = bk[h * 64 + j * 16 + l16];
        bvv[j] = bv[h * 64 + j * 16 + l16];
    }

#pragma unroll
    for (int i = 0; i < 2; ++i)
#pragma unroll
        for (int j = 0; j < 4; ++j) {
            int d = j * 16 + l16;
            int s = s0 + w * 32 + i * 16 + lg * 4;
            ushort4 pv;
            pv.x = f2bf(av[i][j][0] + bvv[j]);
            pv.y = f2bf(av[i][j][1] + bvv[j]);
            pv.z = f2bf(av[i][j][2] + bvv[j]);
            pv.w = f2bf(av[i][j][3] + bvv[j]);
            *(ushort4*)&Vt[((size_t)bh * NHD + d) * NS + s] = pv;
        }

    __syncthreads();
#pragma unroll
    for (int i = 0; i < 2; ++i)
#pragma unroll
        for (int j = 0; j < 4; ++j)
#pragma unroll
            for (int r = 0; r < 4; ++r) {
                int s = w * 32 + i * 16 + lg * 4 + r;
                xs[s * 72 + j * 16 + l16] = f2bf(aq[i][j][r] + bqv[j]);
                zs[s * 72 + j * 16 + l16] = f2bf(ak[i][j][r] + bkv[j]);
            }
    __syncthreads();
#pragma unroll
    for (int c = 0; c < 4; ++c) {
        int chunk = c * 256 + t;
        int row   = chunk >> 3;
        int c8    = chunk & 7;
        short8 qv = *(const short8*)&xs[row * 72 + c8 * 8];
        short8 kv = *(const short8*)&zs[row * 72 + c8 * 8];
        *(short8*)&Q[((size_t)bh * NS + s0 + row) * 64 + c8 * 8] = qv;
        *(short8*)&K[((size_t)bh * NS + s0 + row) * 64 + c8 * 8] = kv;
    }
}

// ---------------------------------------------------------------------------
// Kernel 1c: Wo fp32 -> bf16.
// ---------------------------------------------------------------------------
__global__ __launch_bounds__(256) void wo_cast(
    const float* __restrict__ Wo, ushort* __restrict__ Wob)
{
    int i = (blockIdx.x * 256 + threadIdx.x) * 8;
    float4 a = *(const float4*)&Wo[i];
    float4 b = *(const float4*)&Wo[i + 4];
    short8 o;
    ((ushort*)&o)[0] = f2bf(a.x); ((ushort*)&o)[1] = f2bf(a.y);
    ((ushort*)&o)[2] = f2bf(a.z); ((ushort*)&o)[3] = f2bf(a.w);
    ((ushort*)&o)[4] = f2bf(b.x); ((ushort*)&o)[5] = f2bf(b.y);
    ((ushort*)&o)[6] = f2bf(b.z); ((ushort*)&o)[7] = f2bf(b.w);
    *(short8*)&Wob[i] = o;
}

// ---------------------------------------------------------------------------
// Kernel 2: MFMA flash attention, SWAPPED operands (computes S^T and O^T).
// mfma(kf,qf): D[row=lg*4+r][col=l16] = S^T[k=stt*16+lg*4+r][q=l16] -> each
// lane holds 16 k-scores for ONE q column -> in-register row reduce + only
// 2 shuffle steps (over lg). PV swapped too: O^T = V^T P, identical LDS reads.
// Scores in log2 domain (log2e folded into Q pre-scale); T13 defer-max.
// ---------------------------------------------------------------------------
__global__ __launch_bounds__(256) void flash_attn(
    const ushort* __restrict__ Q, const ushort* __restrict__ K,
    const ushort* __restrict__ Vt, ushort* __restrict__ A)
{
    int qt = (gridDim.x - 1) - blockIdx.x;   // heavy (large qt) first
    int bh = blockIdx.y;
    int h = bh & (NH - 1), b = bh >> 4;

    __shared__ __align__(16) ushort k_lds[64 * 64];
    __shared__ __align__(16) ushort v_lds[64 * 64];
    __shared__ __align__(16) ushort p_lds[4][16 * 72];

    int t = threadIdx.x, w = t >> 6, l = t & 63;
    int l16 = l & 15, lg = l >> 4;

    const ushort* Qb = Q + (size_t)bh * NS * NHD;
    const ushort* Kb = K + (size_t)bh * NS * NHD;
    const ushort* Vb = Vt + (size_t)bh * NHD * NS;

    int q0 = qt * 64;

    // Q fragment, pre-scaled by 1/sqrt(64) * log2(e)  (exp2 domain)
    const float QSCALE = 0.125f * 1.44269504088896f;
    short8 qf[2];
#pragma unroll
    for (int c = 0; c < 2; ++c) {
        short8 raw = *(const short8*)&Qb[(size_t)(q0 + w * 16 + l16) * 64 + c * 32 + lg * 8];
#pragma unroll
        for (int j = 0; j < 8; ++j)
            ((ushort*)&qf[c])[j] = f2bf(bf2f(((ushort*)&raw)[j]) * QSCALE);
    }

    // ob[d0][r] = O[q=l16][d0*16+lg*4+r]; m/ln per lane (its q column)
    floatx4 ob[4];
#pragma unroll
    for (int d = 0; d < 4; ++d) ob[d] = (floatx4){0.f, 0.f, 0.f, 0.f};
    float m = -1e30f, ln = 0.f;

    int rrow = t >> 3, rcb = (t & 7) * 8;
    short8 kpre[2], vpre[2];
#pragma unroll
    for (int p = 0; p < 2; ++p) {
        kpre[p] = *(const short8*)&Kb[(size_t)(p * 32 + rrow) * 64 + rcb];
        vpre[p] = *(const short8*)&Vb[(size_t)(p * 32 + rrow) * NS + rcb];
    }

    for (int kt = 0; kt <= qt; ++kt) {
        if (kt) __syncthreads();
#pragma unroll
        for (int p = 0; p < 2; ++p) {
            *(short8*)((char*)k_lds + SWZ(p * 32 + rrow, rcb * 2)) = kpre[p];
            *(short8*)((char*)v_lds + SWZ(p * 32 + rrow, rcb * 2)) = vpre[p];
        }
        __syncthreads();
        if (kt < qt) {
#pragma unroll
            for (int p = 0; p < 2; ++p) {
                kpre[p] = *(const short8*)&Kb[(size_t)((kt + 1) * 64 + p * 32 + rrow) * 64 + rcb];
                vpre[p] = *(const short8*)&Vb[(size_t)(p * 32 + rrow) * NS + (kt + 1) * 64 + rcb];
            }
        }

        // ---- S^T tiles: sv[stt][r] = S[k=stt*16+lg*4+r][q=l16] (log2 dom.)
        floatx4 sv[4];
#pragma unroll
        for (int stt = 0; stt < 4; ++stt) {
            floatx4 acc = {0.f, 0.f, 0.f, 0.f};
#pragma unroll
            for (int c = 0; c < 2; ++c) {
                int row = stt * 16 + l16;
                short8 kf = *(const short8*)((const char*)k_lds +
                                             SWZ(row, c * 64 + lg * 16));
                acc = __builtin_amdgcn_mfma_f32_16x16x32_bf16(kf, qf[c], acc, 0, 0, 0);
            }
            sv[stt] = acc;
        }
        if (kt == qt) {
#pragma unroll
            for (int stt = 0; stt < 4; ++stt)
#pragma unroll
                for (int r = 0; r < 4; ++r)
                    if (stt * 16 + lg * 4 + r > w * 16 + l16) sv[stt][r] = -1e30f;
        }

        // ---- softmax: in-register max over 16, 2 shuffle steps over lg ----
        float p01 = fmaxf(fmaxf(sv[0][0], sv[0][1]), fmaxf(sv[0][2], sv[0][3]));
        float p23 = fmaxf(fmaxf(sv[1][0], sv[1][1]), fmaxf(sv[1][2], sv[1][3]));
        float p45 = fmaxf(fmaxf(sv[2][0], sv[2][1]), fmaxf(sv[2][2], sv[2][3]));
        float p67 = fmaxf(fmaxf(sv[3][0], sv[3][1]), fmaxf(sv[3][2], sv[3][3]));
        float pmax = fmaxf(fmaxf(p01, p23), fmaxf(p45, p67));
        pmax = fmaxf(pmax, __shfl_xor(pmax, 16, 64));
        pmax = fmaxf(pmax, __shfl_xor(pmax, 32, 64));

        if (!__all(pmax - m <= 8.0f)) {       // T13 defer-max (log2 units)
            float mn = fmaxf(m, pmax);
            float al = exp2f(m - mn);
            m = mn;
            ln *= al;
#pragma unroll
            for (int d = 0; d < 4; ++d)
#pragma unroll
                for (int r = 0; r < 4; ++r) ob[d][r] *= al;
        }

        float rs = 0.f;
#pragma unroll
        for (int stt = 0; stt < 4; ++stt)
#pragma unroll
            for (int r = 0; r < 4; ++r) {
                float p = exp2f(sv[stt][r] - m);
                sv[stt][r] = p;
                rs += p;
            }
        rs += __shfl_xor(rs, 16, 64);
        rs += __shfl_xor(rs, 32, 64);
        ln += rs;

        // ---- P -> p_lds[q][k] (ushort4 packed), then PV: O^T = V^T P ----
#pragma unroll
        for (int stt = 0; stt < 4; ++stt) {
            ushort4 pk;
            pk.x = f2bf(sv[stt][0]); pk.y = f2bf(sv[stt][1]);
            pk.z = f2bf(sv[stt][2]); pk.w = f2bf(sv[stt][3]);
            *(ushort4*)&p_lds[w][l16 * 72 + stt * 16 + lg * 4] = pk;
        }

#pragma unroll
        for (int ks = 0; ks < 2; ++ks) {
            short8 pf = *(const short8*)((const char*)&p_lds[w][0] +
                                         (l16 * 144 + ks * 64 + lg * 16));
#pragma unroll
            for (int d = 0; d < 4; ++d) {
                int vrow = d * 16 + l16;
                short8 vf = *(const short8*)((const char*)v_lds +
                                             SWZ(vrow, ks * 64 + lg * 16));
                ob[d] = __builtin_amdgcn_mfma_f32_16x16x32_bf16(vf, pf, ob[d], 0, 0, 0);
            }
        }
    }

    // epilogue: lane owns q=l16 col; d = d0*16 + lg*4 + r -> ushort4 stores
    float inv = 1.0f / ln;
    int qq = q0 + w * 16 + l16;
#pragma unroll
    for (int d = 0; d < 4; ++d) {
        ushort4 ov;
        ov.x = f2bf(ob[d][0] * inv);
        ov.y = f2bf(ob[d][1] * inv);
        ov.z = f2bf(ob[d][2] * inv);
        ov.w = f2bf(ob[d][3] * inv);
        *(ushort4*)&A[(size_t)(b * NS + qq) * NEMB + h * 64 + d * 16 + lg * 4] = ov;
    }
}

// ---------------------------------------------------------------------------
// Kernel 3: Y = A @ Wo^T + bo via bf16 MFMA, fp32 accum. (unchanged)
// ---------------------------------------------------------------------------
__global__ __launch_bounds__(256) void out_gemm_mfma(
    const ushort* __restrict__ Aq, const ushort* __restrict__ Wob,
    const float* __restrict__ bo, float* __restrict__ Y)
{
    int m0 = blockIdx.x * 128;
    int n0 = blockIdx.y * 128;

    __shared__ __align__(16) ushort As[128 * 64];
    __shared__ __align__(16) ushort Bs[128 * 64];

    int t = threadIdx.x, w = t >> 6, l = t & 63;
    int l16 = l & 15, lg = l >> 4;
    int wr = w >> 1, wc = w & 1;

    floatx4 acc[4][4];
#pragma unroll
    for (int i = 0; i < 4; ++i)
#pragma unroll
        for (int j = 0; j < 4; ++j) acc[i][j] = (floatx4){0.f, 0.f, 0.f, 0.f};

    for (int kt = 0; kt < 16; ++kt) {
        __syncthreads();
#pragma unroll
        for (int i = 0; i < 4; ++i) {
            int chunk = i * 256 + t;
            int row   = chunk >> 3;
            int c16   = chunk & 7;
            short8 av = *(const short8*)&Aq[(size_t)(m0 + row) * 1024 + kt * 64 + c16 * 8];
            *(short8*)((char*)As + SWZ(row, c16 * 16)) = av;
            short8 bv = *(const short8*)&Wob[(size_t)(n0 + row) * 1024 + kt * 64 + c16 * 8];
            *(short8*)((char*)Bs + SWZ(row, c16 * 16)) = bv;
        }
        __syncthreads();
#pragma unroll
        for (int kc = 0; kc < 2; ++kc) {
            short8 af[4], bf[4];
#pragma unroll
            for (int i = 0; i < 4; ++i) {
                int arow = wr * 64 + i * 16 + l16;
                af[i] = *(const short8*)((const char*)As + SWZ(arow, kc * 64 + lg * 16));
                int brow = wc * 64 + i * 16 + l16;
                bf[i] = *(const short8*)((const char*)Bs + SWZ(brow, kc * 64 + lg * 16));
            }
#pragma unroll
            for (int i = 0; i < 4; ++i)
#pragma unroll
                for (int j = 0; j < 4; ++j)
                    acc[i][j] = __builtin_amdgcn_mfma_f32_16x16x32_bf16(
                        af[i], bf[j], acc[i][j], 0, 0, 0);
        }
    }
#pragma unroll
    for (int i = 0; i < 4; ++i)
#pragma unroll
        for (int j = 0; j < 4; ++j) {
            int nn = n0 + wc * 64 + j * 16 + l16;
            float bb = bo[nn];
#pragma unroll
            for (int r = 0; r < 4; ++r) {
                int mm = m0 + wr * 64 + i * 16 + lg * 4 + r;
                Y[(size_t)mm * 1024 + nn] = acc[i][j][r] + bb;
            }
        }
}

// ---------------------------------------------------------------------------
extern "C" void kernel_launch(void* const* d_in, const int* in_sizes, int n_in,
                              void* d_out, int out_size, void* d_ws, size_t ws_size,
                              hipStream_t stream) {
    const float* X  = (const float*)d_in[0];
    const float* Z  = (const float*)d_in[1];
    const float* Wq = (const float*)d_in[2];
    const float* bq = (const float*)d_in[3];
    const float* Wk = (const float*)d_in[4];
    const float* bk = (const float*)d_in[5];
    const float* Wv = (const float*)d_in[6];
    const float* bv = (const float*)d_in[7];
    const float* Wo = (const float*)d_in[8];
    const float* bo = (const float*)d_in[9];
    float* out = (float*)d_out;

    const size_t NQ = (size_t)NB * NH * NS * NHD;   // 4M elems
    ushort* Qd  = (ushort*)d_ws;
    ushort* Kd  = Qd + NQ;
    ushort* Vtd = Kd + NQ;
    ushort* Ad  = Vtd + NQ;
    ushort* Wob = Ad + NQ;

    qkv_mfma<<<dim3(NS / 128, NB * NH), 256, 0, stream>>>(
        X, Z, Wq, bq, Wk, bk, Wv, bv, Qd, Kd, Vtd);
    wo_cast<<<dim3(512), 256, 0, stream>>>(Wo, Wob);
    flash_attn<<<dim3(NS / 64, NB * NH), 256, 0, stream>>>(Qd, Kd, Vtd, Ad);
    out_gemm_mfma<<<dim3(32, 8), 256, 0, stream>>>(Ad, Wob, bo, out);
}

// Round 7
// 119.414 us; speedup vs baseline: 56.2874x; 1.0220x over previous
//
#include <hip/hip_runtime.h>
#include <hip/hip_bf16.h>
#include <math.h>

#define NB   2
#define NS   2048
#define NEMB 1024
#define NH   16
#define NHD  64

typedef __attribute__((ext_vector_type(8))) short short8;
typedef __attribute__((ext_vector_type(4))) float floatx4;

static __device__ __forceinline__ ushort f2bf(float f) {
    union { float f; uint u; } x; x.f = f;
    uint r = (x.u + 0x7FFFu + ((x.u >> 16) & 1u)) >> 16;
    return (ushort)r;
}
static __device__ __forceinline__ float bf2f(ushort u) {
    union { uint u; float f; } x; x.u = ((uint)u) << 16;
    return x.f;
}

#define SWZ(row, bytecol) (((row) * 128 + (bytecol)) ^ (((row) & 7) << 4))

// ---------------------------------------------------------------------------
// Kernel 1: fused QKV projection via MFMA (fp32 in, bf16 out), emits Q, K and
// TRANSPOSED V (Vt[b,h,d,s]) directly. grid = (S/128, B*H), block 256.
// ---------------------------------------------------------------------------
__global__ __launch_bounds__(256) void qkv_mfma(
    const float* __restrict__ X, const float* __restrict__ Z,
    const float* __restrict__ Wq, const float* __restrict__ bq,
    const float* __restrict__ Wk, const float* __restrict__ bk,
    const float* __restrict__ Wv, const float* __restrict__ bv,
    ushort* __restrict__ Q, ushort* __restrict__ K, ushort* __restrict__ Vt)
{
    int st = blockIdx.x, bh = blockIdx.y;
    int h = bh & (NH - 1), b = bh >> 4;
    int s0 = st * 128;

    __shared__ __align__(16) ushort xs[128 * 72];
    __shared__ __align__(16) ushort zs[128 * 72];
    __shared__ __align__(16) ushort wqs[64 * 64], wks[64 * 64], wvs[64 * 64];

    int t = threadIdx.x, w = t >> 6, l = t & 63;
    int l16 = l & 15, lg = l >> 4;

#pragma unroll
    for (int c = 0; c < 4; ++c) {
        int chunk = c * 256 + t;
        int row   = chunk >> 3;
        int c8    = chunk & 7;
        const float* px = &X[(size_t)(b * NS + s0 + row) * NEMB + h * 64 + c8 * 8];
        const float* pz = &Z[(size_t)(b * NS + s0 + row) * NEMB + h * 64 + c8 * 8];
        float4 a0 = *(const float4*)px, a1 = *(const float4*)(px + 4);
        float4 z0 = *(const float4*)pz, z1 = *(const float4*)(pz + 4);
        short8 xv, zv;
        ((ushort*)&xv)[0] = f2bf(a0.x); ((ushort*)&xv)[1] = f2bf(a0.y);
        ((ushort*)&xv)[2] = f2bf(a0.z); ((ushort*)&xv)[3] = f2bf(a0.w);
        ((ushort*)&xv)[4] = f2bf(a1.x); ((ushort*)&xv)[5] = f2bf(a1.y);
        ((ushort*)&xv)[6] = f2bf(a1.z); ((ushort*)&xv)[7] = f2bf(a1.w);
        ((ushort*)&zv)[0] = f2bf(z0.x); ((ushort*)&zv)[1] = f2bf(z0.y);
        ((ushort*)&zv)[2] = f2bf(z0.z); ((ushort*)&zv)[3] = f2bf(z0.w);
        ((ushort*)&zv)[4] = f2bf(z1.x); ((ushort*)&zv)[5] = f2bf(z1.y);
        ((ushort*)&zv)[6] = f2bf(z1.z); ((ushort*)&zv)[7] = f2bf(z1.w);
        *(short8*)((char*)xs + SWZ(row, c8 * 16)) = xv;
        *(short8*)((char*)zs + SWZ(row, c8 * 16)) = zv;
    }
#pragma unroll
    for (int c = 0; c < 2; ++c) {
        int chunk = c * 256 + t;
        int row   = chunk >> 3;
        int c8    = chunk & 7;
        const float* pq = &Wq[(size_t)h * 4096 + row * 64 + c8 * 8];
        const float* pk = &Wk[(size_t)h * 4096 + row * 64 + c8 * 8];
        const float* pv = &Wv[(size_t)h * 4096 + row * 64 + c8 * 8];
        float4 q0 = *(const float4*)pq, q1 = *(const float4*)(pq + 4);
        float4 k0 = *(const float4*)pk, k1 = *(const float4*)(pk + 4);
        float4 v0 = *(const float4*)pv, v1 = *(const float4*)(pv + 4);
        short8 qv, kv, vv;
#pragma unroll
        for (int j = 0; j < 4; ++j) {
            ((ushort*)&qv)[j]     = f2bf(((const float*)&q0)[j]);
            ((ushort*)&qv)[j + 4] = f2bf(((const float*)&q1)[j]);
            ((ushort*)&kv)[j]     = f2bf(((const float*)&k0)[j]);
            ((ushort*)&kv)[j + 4] = f2bf(((const float*)&k1)[j]);
            ((ushort*)&vv)[j]     = f2bf(((const float*)&v0)[j]);
            ((ushort*)&vv)[j + 4] = f2bf(((const float*)&v1)[j]);
        }
        *(short8*)((char*)wqs + SWZ(row, c8 * 16)) = qv;
        *(short8*)((char*)wks + SWZ(row, c8 * 16)) = kv;
        *(short8*)((char*)wvs + SWZ(row, c8 * 16)) = vv;
    }
    __syncthreads();

    floatx4 aq[2][4], ak[2][4], av[2][4];
#pragma unroll
    for (int i = 0; i < 2; ++i)
#pragma unroll
        for (int j = 0; j < 4; ++j) {
            aq[i][j] = (floatx4){0.f, 0.f, 0.f, 0.f};
            ak[i][j] = (floatx4){0.f, 0.f, 0.f, 0.f};
            av[i][j] = (floatx4){0.f, 0.f, 0.f, 0.f};
        }

#pragma unroll
    for (int kc = 0; kc < 2; ++kc) {
        short8 xa[2], za[2];
#pragma unroll
        for (int i = 0; i < 2; ++i) {
            int row = w * 32 + i * 16 + l16;
            xa[i] = *(const short8*)((const char*)xs + SWZ(row, kc * 64 + lg * 16));
            za[i] = *(const short8*)((const char*)zs + SWZ(row, kc * 64 + lg * 16));
        }
#pragma unroll
        for (int j = 0; j < 4; ++j) {
            int row = j * 16 + l16;
            short8 wqf = *(const short8*)((const char*)wqs + SWZ(row, kc * 64 + lg * 16));
            short8 wkf = *(const short8*)((const char*)wks + SWZ(row, kc * 64 + lg * 16));
            short8 wvf = *(const short8*)((const char*)wvs + SWZ(row, kc * 64 + lg * 16));
#pragma unroll
            for (int i = 0; i < 2; ++i) {
                aq[i][j] = __builtin_amdgcn_mfma_f32_16x16x32_bf16(xa[i], wqf, aq[i][j], 0, 0, 0);
                ak[i][j] = __builtin_amdgcn_mfma_f32_16x16x32_bf16(za[i], wkf, ak[i][j], 0, 0, 0);
                av[i][j] = __builtin_amdgcn_mfma_f32_16x16x32_bf16(za[i], wvf, av[i][j], 0, 0, 0);
            }
        }
    }

    float bqv[4], bkv[4], bvv[4];
#pragma unroll
    for (int j = 0; j < 4; ++j) {
        bqv[j] = bq[h * 64 + j * 16 + l16];
        bkv[j] = bk[h * 64 + j * 16 + l16];
        bvv[j] = bv[h * 64 + j * 16 + l16];
    }

#pragma unroll
    for (int i = 0; i < 2; ++i)
#pragma unroll
        for (int j = 0; j < 4; ++j) {
            int d = j * 16 + l16;
            int s = s0 + w * 32 + i * 16 + lg * 4;
            ushort4 pv;
            pv.x = f2bf(av[i][j][0] + bvv[j]);
            pv.y = f2bf(av[i][j][1] + bvv[j]);
            pv.z = f2bf(av[i][j][2] + bvv[j]);
            pv.w = f2bf(av[i][j][3] + bvv[j]);
            *(ushort4*)&Vt[((size_t)bh * NHD + d) * NS + s] = pv;
        }

    __syncthreads();
#pragma unroll
    for (int i = 0; i < 2; ++i)
#pragma unroll
        for (int j = 0; j < 4; ++j)
#pragma unroll
            for (int r = 0; r < 4; ++r) {
                int s = w * 32 + i * 16 + lg * 4 + r;
                xs[s * 72 + j * 16 + l16] = f2bf(aq[i][j][r] + bqv[j]);
                zs[s * 72 + j * 16 + l16] = f2bf(ak[i][j][r] + bkv[j]);
            }
    __syncthreads();
#pragma unroll
    for (int c = 0; c < 4; ++c) {
        int chunk = c * 256 + t;
        int row   = chunk >> 3;
        int c8    = chunk & 7;
        short8 qv = *(const short8*)&xs[row * 72 + c8 * 8];
        short8 kv = *(const short8*)&zs[row * 72 + c8 * 8];
        *(short8*)&Q[((size_t)bh * NS + s0 + row) * 64 + c8 * 8] = qv;
        *(short8*)&K[((size_t)bh * NS + s0 + row) * 64 + c8 * 8] = kv;
    }
}

// ---------------------------------------------------------------------------
// Kernel 1c: Wo fp32 -> bf16.
// ---------------------------------------------------------------------------
__global__ __launch_bounds__(256) void wo_cast(
    const float* __restrict__ Wo, ushort* __restrict__ Wob)
{
    int i = (blockIdx.x * 256 + threadIdx.x) * 8;
    float4 a = *(const float4*)&Wo[i];
    float4 b = *(const float4*)&Wo[i + 4];
    short8 o;
    ((ushort*)&o)[0] = f2bf(a.x); ((ushort*)&o)[1] = f2bf(a.y);
    ((ushort*)&o)[2] = f2bf(a.z); ((ushort*)&o)[3] = f2bf(a.w);
    ((ushort*)&o)[4] = f2bf(b.x); ((ushort*)&o)[5] = f2bf(b.y);
    ((ushort*)&o)[6] = f2bf(b.z); ((ushort*)&o)[7] = f2bf(b.w);
    *(short8*)&Wob[i] = o;
}

// ---------------------------------------------------------------------------
// Kernel 2: MFMA flash attention, swapped operands + WITHIN-BLOCK SPLIT-K.
// 8 waves / 512 threads: wave-group g = w>>2 handles KV tiles kt == g (mod 2)
// with its own K/V LDS double of the same 64 q rows; log-domain merge at end.
// Halves the sequential epoch count per block (critical path), raises
// waves/CU. Scores in exp2 domain; T13 defer-max.
// ---------------------------------------------------------------------------
__global__ __launch_bounds__(512) void flash_attn(
    const ushort* __restrict__ Q, const ushort* __restrict__ K,
    const ushort* __restrict__ Vt, ushort* __restrict__ A)
{
    int qt = (gridDim.x - 1) - blockIdx.x;   // heavy (large qt) first
    int bh = blockIdx.y;
    int h = bh & (NH - 1), b = bh >> 4;

    __shared__ __align__(16) ushort k_lds[2][64 * 64];
    __shared__ __align__(16) ushort v_lds[2][64 * 64];
    __shared__ __align__(16) ushort p_lds[8][16 * 72];

    int t = threadIdx.x, w = t >> 6, l = t & 63;
    int g = w >> 2, w4 = w & 3;
    int l16 = l & 15, lg = l >> 4;

    const ushort* Qb = Q + (size_t)bh * NS * NHD;
    const ushort* Kb = K + (size_t)bh * NS * NHD;
    const ushort* Vb = Vt + (size_t)bh * NHD * NS;

    int q0 = qt * 64;

    // Q fragment (same q rows for both groups), pre-scaled into exp2 domain
    const float QSCALE = 0.125f * 1.44269504088896f;
    short8 qf[2];
#pragma unroll
    for (int c = 0; c < 2; ++c) {
        short8 raw = *(const short8*)&Qb[(size_t)(q0 + w4 * 16 + l16) * 64 + c * 32 + lg * 8];
#pragma unroll
        for (int j = 0; j < 8; ++j)
            ((ushort*)&qf[c])[j] = f2bf(bf2f(((ushort*)&raw)[j]) * QSCALE);
    }

    floatx4 ob[4];
#pragma unroll
    for (int d = 0; d < 4; ++d) ob[d] = (floatx4){0.f, 0.f, 0.f, 0.f};
    float m = -1e30f, ln = 0.f;

    // group-local staging assignment (256 threads stage 8KB K + 8KB V)
    int gt = t & 255;
    int rrow = gt >> 3, rcb = (gt & 7) * 8;

    short8 kpre[2], vpre[2];
    if (g <= qt) {                 // group 0 always; group 1 iff qt >= 1
#pragma unroll
        for (int p = 0; p < 2; ++p) {
            kpre[p] = *(const short8*)&Kb[(size_t)(g * 64 + p * 32 + rrow) * 64 + rcb];
            vpre[p] = *(const short8*)&Vb[(size_t)(p * 32 + rrow) * NS + g * 64 + rcb];
        }
    }

    int nt = qt / 2 + 1;           // lockstep epochs (groups differ by <=1 tile)
    for (int it = 0; it < nt; ++it) {
        int kt = g + 2 * it;
        bool active = (kt <= qt);
        if (it) __syncthreads();
        if (active) {
#pragma unroll
            for (int p = 0; p < 2; ++p) {
                *(short8*)((char*)k_lds[g] + SWZ(p * 32 + rrow, rcb * 2)) = kpre[p];
                *(short8*)((char*)v_lds[g] + SWZ(p * 32 + rrow, rcb * 2)) = vpre[p];
            }
        }
        __syncthreads();
        if (active && kt + 2 <= qt) {
#pragma unroll
            for (int p = 0; p < 2; ++p) {
                kpre[p] = *(const short8*)&Kb[(size_t)((kt + 2) * 64 + p * 32 + rrow) * 64 + rcb];
                vpre[p] = *(const short8*)&Vb[(size_t)(p * 32 + rrow) * NS + (kt + 2) * 64 + rcb];
            }
        }
        if (!active) continue;

        // ---- S^T: sv[stt][r] = S[k=stt*16+lg*4+r][q=l16] (log2 domain) ----
        floatx4 sv[4];
#pragma unroll
        for (int stt = 0; stt < 4; ++stt) {
            floatx4 acc = {0.f, 0.f, 0.f, 0.f};
#pragma unroll
            for (int c = 0; c < 2; ++c) {
                int row = stt * 16 + l16;
                short8 kf = *(const short8*)((const char*)k_lds[g] +
                                             SWZ(row, c * 64 + lg * 16));
                acc = __builtin_amdgcn_mfma_f32_16x16x32_bf16(kf, qf[c], acc, 0, 0, 0);
            }
            sv[stt] = acc;
        }
        if (kt == qt) {
#pragma unroll
            for (int stt = 0; stt < 4; ++stt)
#pragma unroll
                for (int r = 0; r < 4; ++r)
                    if (stt * 16 + lg * 4 + r > w4 * 16 + l16) sv[stt][r] = -1e30f;
        }

        // ---- softmax: in-register 16-max + 2 shuffles ----
        float p01 = fmaxf(fmaxf(sv[0][0], sv[0][1]), fmaxf(sv[0][2], sv[0][3]));
        float p23 = fmaxf(fmaxf(sv[1][0], sv[1][1]), fmaxf(sv[1][2], sv[1][3]));
        float p45 = fmaxf(fmaxf(sv[2][0], sv[2][1]), fmaxf(sv[2][2], sv[2][3]));
        float p67 = fmaxf(fmaxf(sv[3][0], sv[3][1]), fmaxf(sv[3][2], sv[3][3]));
        float pmax = fmaxf(fmaxf(p01, p23), fmaxf(p45, p67));
        pmax = fmaxf(pmax, __shfl_xor(pmax, 16, 64));
        pmax = fmaxf(pmax, __shfl_xor(pmax, 32, 64));

        if (!__all(pmax - m <= 8.0f)) {       // T13 defer-max (log2 units)
            float mn = fmaxf(m, pmax);
            float al = exp2f(m - mn);
            m = mn;
            ln *= al;
#pragma unroll
            for (int d = 0; d < 4; ++d)
#pragma unroll
                for (int r = 0; r < 4; ++r) ob[d][r] *= al;
        }

        float rs = 0.f;
#pragma unroll
        for (int stt = 0; stt < 4; ++stt)
#pragma unroll
            for (int r = 0; r < 4; ++r) {
                float p = exp2f(sv[stt][r] - m);
                sv[stt][r] = p;
                rs += p;
            }
        rs += __shfl_xor(rs, 16, 64);
        rs += __shfl_xor(rs, 32, 64);
        ln += rs;

        // ---- P -> p_lds[q][k], then PV: O^T = V^T P ----
#pragma unroll
        for (int stt = 0; stt < 4; ++stt) {
            ushort4 pk;
            pk.x = f2bf(sv[stt][0]); pk.y = f2bf(sv[stt][1]);
            pk.z = f2bf(sv[stt][2]); pk.w = f2bf(sv[stt][3]);
            *(ushort4*)&p_lds[w][l16 * 72 + stt * 16 + lg * 4] = pk;
        }

#pragma unroll
        for (int ks = 0; ks < 2; ++ks) {
            short8 pf = *(const short8*)((const char*)&p_lds[w][0] +
                                         (l16 * 144 + ks * 64 + lg * 16));
#pragma unroll
            for (int d = 0; d < 4; ++d) {
                int vrow = d * 16 + l16;
                short8 vf = *(const short8*)((const char*)v_lds[g] +
                                             SWZ(vrow, ks * 64 + lg * 16));
                ob[d] = __builtin_amdgcn_mfma_f32_16x16x32_bf16(vf, pf, ob[d], 0, 0, 0);
            }
        }
    }

    // ---- merge group 1 into group 0 (log-domain combine), then store ----
    __syncthreads();
    float* mrg = (float*)&k_lds[0][0];       // 4 waves x 64 lanes x 20 floats = 20KB
    if (g == 1) {
        int base = (w4 * 64 + l) * 20;
#pragma unroll
        for (int d = 0; d < 4; ++d)
            *(float4*)&mrg[base + d * 4] = (float4){ob[d][0], ob[d][1], ob[d][2], ob[d][3]};
        mrg[base + 16] = m;
        mrg[base + 17] = ln;
    }
    __syncthreads();
    if (g == 0) {
        int base = (w4 * 64 + l) * 20;
        float m1  = mrg[base + 16];
        float ln1 = mrg[base + 17];
        float ms  = fmaxf(m, m1);
        float a0  = exp2f(m - ms);
        float a1  = exp2f(m1 - ms);
        float inv = 1.0f / (ln * a0 + ln1 * a1);
        int qq = q0 + w4 * 16 + l16;
#pragma unroll
        for (int d = 0; d < 4; ++d) {
            float4 o1 = *(const float4*)&mrg[base + d * 4];
            ushort4 ov;
            ov.x = f2bf((ob[d][0] * a0 + o1.x * a1) * inv);
            ov.y = f2bf((ob[d][1] * a0 + o1.y * a1) * inv);
            ov.z = f2bf((ob[d][2] * a0 + o1.z * a1) * inv);
            ov.w = f2bf((ob[d][3] * a0 + o1.w * a1) * inv);
            *(ushort4*)&A[(size_t)(b * NS + qq) * NEMB + h * 64 + d * 16 + lg * 4] = ov;
        }
    }
}

// ---------------------------------------------------------------------------
// Kernel 3: Y = A @ Wo^T + bo via bf16 MFMA, fp32 accum. (unchanged)
// ---------------------------------------------------------------------------
__global__ __launch_bounds__(256) void out_gemm_mfma(
    const ushort* __restrict__ Aq, const ushort* __restrict__ Wob,
    const float* __restrict__ bo, float* __restrict__ Y)
{
    int m0 = blockIdx.x * 128;
    int n0 = blockIdx.y * 128;

    __shared__ __align__(16) ushort As[128 * 64];
    __shared__ __align__(16) ushort Bs[128 * 64];

    int t = threadIdx.x, w = t >> 6, l = t & 63;
    int l16 = l & 15, lg = l >> 4;
    int wr = w >> 1, wc = w & 1;

    floatx4 acc[4][4];
#pragma unroll
    for (int i = 0; i < 4; ++i)
#pragma unroll
        for (int j = 0; j < 4; ++j) acc[i][j] = (floatx4){0.f, 0.f, 0.f, 0.f};

    for (int kt = 0; kt < 16; ++kt) {
        __syncthreads();
#pragma unroll
        for (int i = 0; i < 4; ++i) {
            int chunk = i * 256 + t;
            int row   = chunk >> 3;
            int c16   = chunk & 7;
            short8 av = *(const short8*)&Aq[(size_t)(m0 + row) * 1024 + kt * 64 + c16 * 8];
            *(short8*)((char*)As + SWZ(row, c16 * 16)) = av;
            short8 bv = *(const short8*)&Wob[(size_t)(n0 + row) * 1024 + kt * 64 + c16 * 8];
            *(short8*)((char*)Bs + SWZ(row, c16 * 16)) = bv;
        }
        __syncthreads();
#pragma unroll
        for (int kc = 0; kc < 2; ++kc) {
            short8 af[4], bf[4];
#pragma unroll
            for (int i = 0; i < 4; ++i) {
                int arow = wr * 64 + i * 16 + l16;
                af[i] = *(const short8*)((const char*)As + SWZ(arow, kc * 64 + lg * 16));
                int brow = wc * 64 + i * 16 + l16;
                bf[i] = *(const short8*)((const char*)Bs + SWZ(brow, kc * 64 + lg * 16));
            }
#pragma unroll
            for (int i = 0; i < 4; ++i)
#pragma unroll
                for (int j = 0; j < 4; ++j)
                    acc[i][j] = __builtin_amdgcn_mfma_f32_16x16x32_bf16(
                        af[i], bf[j], acc[i][j], 0, 0, 0);
        }
    }
#pragma unroll
    for (int i = 0; i < 4; ++i)
#pragma unroll
        for (int j = 0; j < 4; ++j) {
            int nn = n0 + wc * 64 + j * 16 + l16;
            float bb = bo[nn];
#pragma unroll
            for (int r = 0; r < 4; ++r) {
                int mm = m0 + wr * 64 + i * 16 + lg * 4 + r;
                Y[(size_t)mm * 1024 + nn] = acc[i][j][r] + bb;
            }
        }
}

// ---------------------------------------------------------------------------
extern "C" void kernel_launch(void* const* d_in, const int* in_sizes, int n_in,
                              void* d_out, int out_size, void* d_ws, size_t ws_size,
                              hipStream_t stream) {
    const float* X  = (const float*)d_in[0];
    const float* Z  = (const float*)d_in[1];
    const float* Wq = (const float*)d_in[2];
    const float* bq = (const float*)d_in[3];
    const float* Wk = (const float*)d_in[4];
    const float* bk = (const float*)d_in[5];
    const float* Wv = (const float*)d_in[6];
    const float* bv = (const float*)d_in[7];
    const float* Wo = (const float*)d_in[8];
    const float* bo = (const float*)d_in[9];
    float* out = (float*)d_out;

    const size_t NQ = (size_t)NB * NH * NS * NHD;   // 4M elems
    ushort* Qd  = (ushort*)d_ws;
    ushort* Kd  = Qd + NQ;
    ushort* Vtd = Kd + NQ;
    ushort* Ad  = Vtd + NQ;
    ushort* Wob = Ad + NQ;

    qkv_mfma<<<dim3(NS / 128, NB * NH), 256, 0, stream>>>(
        X, Z, Wq, bq, Wk, bk, Wv, bv, Qd, Kd, Vtd);
    wo_cast<<<dim3(512), 256, 0, stream>>>(Wo, Wob);
    flash_attn<<<dim3(NS / 64, NB * NH), 512, 0, stream>>>(Qd, Kd, Vtd, Ad);
    out_gemm_mfma<<<dim3(32, 8), 256, 0, stream>>>(Ad, Wob, bo, out);
}

// Round 8
// 113.009 us; speedup vs baseline: 59.4773x; 1.0567x over previous
//
#include <hip/hip_runtime.h>
#include <hip/hip_bf16.h>
#include <math.h>

#define NB   2
#define NS   2048
#define NEMB 1024
#define NH   16
#define NHD  64

typedef __attribute__((ext_vector_type(8))) short short8;
typedef __attribute__((ext_vector_type(4))) float floatx4;

static __device__ __forceinline__ ushort f2bf(float f) {
    union { float f; uint u; } x; x.f = f;
    uint r = (x.u + 0x7FFFu + ((x.u >> 16) & 1u)) >> 16;
    return (ushort)r;
}
static __device__ __forceinline__ float bf2f(ushort u) {
    union { uint u; float f; } x; x.u = ((uint)u) << 16;
    return x.f;
}

#define SWZ(row, bytecol) (((row) * 128 + (bytecol)) ^ (((row) & 7) << 4))

// ---------------------------------------------------------------------------
// Kernel 1: fused QKV projection via MFMA (fp32 in, bf16 out), emits Q, K and
// TRANSPOSED V (Vt[b,h,d,s]) directly. grid = (S/128, B*H), block 256.
// ---------------------------------------------------------------------------
__global__ __launch_bounds__(256) void qkv_mfma(
    const float* __restrict__ X, const float* __restrict__ Z,
    const float* __restrict__ Wq, const float* __restrict__ bq,
    const float* __restrict__ Wk, const float* __restrict__ bk,
    const float* __restrict__ Wv, const float* __restrict__ bv,
    ushort* __restrict__ Q, ushort* __restrict__ K, ushort* __restrict__ Vt)
{
    int st = blockIdx.x, bh = blockIdx.y;
    int h = bh & (NH - 1), b = bh >> 4;
    int s0 = st * 128;

    __shared__ __align__(16) ushort xs[128 * 72];
    __shared__ __align__(16) ushort zs[128 * 72];
    __shared__ __align__(16) ushort wqs[64 * 64], wks[64 * 64], wvs[64 * 64];

    int t = threadIdx.x, w = t >> 6, l = t & 63;
    int l16 = l & 15, lg = l >> 4;

#pragma unroll
    for (int c = 0; c < 4; ++c) {
        int chunk = c * 256 + t;
        int row   = chunk >> 3;
        int c8    = chunk & 7;
        const float* px = &X[(size_t)(b * NS + s0 + row) * NEMB + h * 64 + c8 * 8];
        const float* pz = &Z[(size_t)(b * NS + s0 + row) * NEMB + h * 64 + c8 * 8];
        float4 a0 = *(const float4*)px, a1 = *(const float4*)(px + 4);
        float4 z0 = *(const float4*)pz, z1 = *(const float4*)(pz + 4);
        short8 xv, zv;
        ((ushort*)&xv)[0] = f2bf(a0.x); ((ushort*)&xv)[1] = f2bf(a0.y);
        ((ushort*)&xv)[2] = f2bf(a0.z); ((ushort*)&xv)[3] = f2bf(a0.w);
        ((ushort*)&xv)[4] = f2bf(a1.x); ((ushort*)&xv)[5] = f2bf(a1.y);
        ((ushort*)&xv)[6] = f2bf(a1.z); ((ushort*)&xv)[7] = f2bf(a1.w);
        ((ushort*)&zv)[0] = f2bf(z0.x); ((ushort*)&zv)[1] = f2bf(z0.y);
        ((ushort*)&zv)[2] = f2bf(z0.z); ((ushort*)&zv)[3] = f2bf(z0.w);
        ((ushort*)&zv)[4] = f2bf(z1.x); ((ushort*)&zv)[5] = f2bf(z1.y);
        ((ushort*)&zv)[6] = f2bf(z1.z); ((ushort*)&zv)[7] = f2bf(z1.w);
        *(short8*)((char*)xs + SWZ(row, c8 * 16)) = xv;
        *(short8*)((char*)zs + SWZ(row, c8 * 16)) = zv;
    }
#pragma unroll
    for (int c = 0; c < 2; ++c) {
        int chunk = c * 256 + t;
        int row   = chunk >> 3;
        int c8    = chunk & 7;
        const float* pq = &Wq[(size_t)h * 4096 + row * 64 + c8 * 8];
        const float* pk = &Wk[(size_t)h * 4096 + row * 64 + c8 * 8];
        const float* pv = &Wv[(size_t)h * 4096 + row * 64 + c8 * 8];
        float4 q0 = *(const float4*)pq, q1 = *(const float4*)(pq + 4);
        float4 k0 = *(const float4*)pk, k1 = *(const float4*)(pk + 4);
        float4 v0 = *(const float4*)pv, v1 = *(const float4*)(pv + 4);
        short8 qv, kv, vv;
#pragma unroll
        for (int j = 0; j < 4; ++j) {
            ((ushort*)&qv)[j]     = f2bf(((const float*)&q0)[j]);
            ((ushort*)&qv)[j + 4] = f2bf(((const float*)&q1)[j]);
            ((ushort*)&kv)[j]     = f2bf(((const float*)&k0)[j]);
            ((ushort*)&kv)[j + 4] = f2bf(((const float*)&k1)[j]);
            ((ushort*)&vv)[j]     = f2bf(((const float*)&v0)[j]);
            ((ushort*)&vv)[j + 4] = f2bf(((const float*)&v1)[j]);
        }
        *(short8*)((char*)wqs + SWZ(row, c8 * 16)) = qv;
        *(short8*)((char*)wks + SWZ(row, c8 * 16)) = kv;
        *(short8*)((char*)wvs + SWZ(row, c8 * 16)) = vv;
    }
    __syncthreads();

    floatx4 aq[2][4], ak[2][4], av[2][4];
#pragma unroll
    for (int i = 0; i < 2; ++i)
#pragma unroll
        for (int j = 0; j < 4; ++j) {
            aq[i][j] = (floatx4){0.f, 0.f, 0.f, 0.f};
            ak[i][j] = (floatx4){0.f, 0.f, 0.f, 0.f};
            av[i][j] = (floatx4){0.f, 0.f, 0.f, 0.f};
        }

#pragma unroll
    for (int kc = 0; kc < 2; ++kc) {
        short8 xa[2], za[2];
#pragma unroll
        for (int i = 0; i < 2; ++i) {
            int row = w * 32 + i * 16 + l16;
            xa[i] = *(const short8*)((const char*)xs + SWZ(row, kc * 64 + lg * 16));
            za[i] = *(const short8*)((const char*)zs + SWZ(row, kc * 64 + lg * 16));
        }
#pragma unroll
        for (int j = 0; j < 4; ++j) {
            int row = j * 16 + l16;
            short8 wqf = *(const short8*)((const char*)wqs + SWZ(row, kc * 64 + lg * 16));
            short8 wkf = *(const short8*)((const char*)wks + SWZ(row, kc * 64 + lg * 16));
            short8 wvf = *(const short8*)((const char*)wvs + SWZ(row, kc * 64 + lg * 16));
#pragma unroll
            for (int i = 0; i < 2; ++i) {
                aq[i][j] = __builtin_amdgcn_mfma_f32_16x16x32_bf16(xa[i], wqf, aq[i][j], 0, 0, 0);
                ak[i][j] = __builtin_amdgcn_mfma_f32_16x16x32_bf16(za[i], wkf, ak[i][j], 0, 0, 0);
                av[i][j] = __builtin_amdgcn_mfma_f32_16x16x32_bf16(za[i], wvf, av[i][j], 0, 0, 0);
            }
        }
    }

    float bqv[4], bkv[4], bvv[4];
#pragma unroll
    for (int j = 0; j < 4; ++j) {
        bqv[j] = bq[h * 64 + j * 16 + l16];
        bkv[j] = bk[h * 64 + j * 16 + l16];
        bvv[j] = bv[h * 64 + j * 16 + l16];
    }

#pragma unroll
    for (int i = 0; i < 2; ++i)
#pragma unroll
        for (int j = 0; j < 4; ++j) {
            int d = j * 16 + l16;
            int s = s0 + w * 32 + i * 16 + lg * 4;
            ushort4 pv;
            pv.x = f2bf(av[i][j][0] + bvv[j]);
            pv.y = f2bf(av[i][j][1] + bvv[j]);
            pv.z = f2bf(av[i][j][2] + bvv[j]);
            pv.w = f2bf(av[i][j][3] + bvv[j]);
            *(ushort4*)&Vt[((size_t)bh * NHD + d) * NS + s] = pv;
        }

    __syncthreads();
#pragma unroll
    for (int i = 0; i < 2; ++i)
#pragma unroll
        for (int j = 0; j < 4; ++j)
#pragma unroll
            for (int r = 0; r < 4; ++r) {
                int s = w * 32 + i * 16 + lg * 4 + r;
                xs[s * 72 + j * 16 + l16] = f2bf(aq[i][j][r] + bqv[j]);
                zs[s * 72 + j * 16 + l16] = f2bf(ak[i][j][r] + bkv[j]);
            }
    __syncthreads();
#pragma unroll
    for (int c = 0; c < 4; ++c) {
        int chunk = c * 256 + t;
        int row   = chunk >> 3;
        int c8    = chunk & 7;
        short8 qv = *(const short8*)&xs[row * 72 + c8 * 8];
        short8 kv = *(const short8*)&zs[row * 72 + c8 * 8];
        *(short8*)&Q[((size_t)bh * NS + s0 + row) * 64 + c8 * 8] = qv;
        *(short8*)&K[((size_t)bh * NS + s0 + row) * 64 + c8 * 8] = kv;
    }
}

// ---------------------------------------------------------------------------
// Kernel 1c: Wo fp32 -> bf16.
// ---------------------------------------------------------------------------
__global__ __launch_bounds__(256) void wo_cast(
    const float* __restrict__ Wo, ushort* __restrict__ Wob)
{
    int i = (blockIdx.x * 256 + threadIdx.x) * 8;
    float4 a = *(const float4*)&Wo[i];
    float4 b = *(const float4*)&Wo[i + 4];
    short8 o;
    ((ushort*)&o)[0] = f2bf(a.x); ((ushort*)&o)[1] = f2bf(a.y);
    ((ushort*)&o)[2] = f2bf(a.z); ((ushort*)&o)[3] = f2bf(a.w);
    ((ushort*)&o)[4] = f2bf(b.x); ((ushort*)&o)[5] = f2bf(b.y);
    ((ushort*)&o)[6] = f2bf(b.z); ((ushort*)&o)[7] = f2bf(b.w);
    *(short8*)&Wob[i] = o;
}

// ---------------------------------------------------------------------------
// Kernel 2: MFMA flash attention, swapped operands, Q-PAIR SHARING:
// 8 waves / 512 threads, 128 q rows per block (wave w owns rows w*16..+15),
// ONE shared K/V tile per epoch (16KB), double-buffered -> ONE barrier/epoch:
//   barrier -> issue next-tile global loads -> compute cur -> write next buf.
// Causality: wave w active for kt <= 2*tq + (w>>2); waves differ by <=1 tile.
// Scores in exp2 domain; T13 defer-max. No merge phase (waves own q rows).
// ---------------------------------------------------------------------------
__global__ __launch_bounds__(512) void flash_attn(
    const ushort* __restrict__ Q, const ushort* __restrict__ K,
    const ushort* __restrict__ Vt, ushort* __restrict__ A)
{
    int tq = (gridDim.x - 1) - blockIdx.x;   // q-pair index, heavy first
    int bh = blockIdx.y;
    int h = bh & (NH - 1), b = bh >> 4;

    __shared__ __align__(16) ushort k_lds[2][64 * 64];
    __shared__ __align__(16) ushort v_lds[2][64 * 64];
    __shared__ __align__(16) ushort p_lds[8][16 * 72];

    int t = threadIdx.x, w = t >> 6, l = t & 63;
    int l16 = l & 15, lg = l >> 4;
    int w4 = w & 3, wh = w >> 2;

    const ushort* Qb = Q + (size_t)bh * NS * NHD;
    const ushort* Kb = K + (size_t)bh * NS * NHD;
    const ushort* Vb = Vt + (size_t)bh * NHD * NS;

    int q0 = tq * 128;

    // Q fragment: wave w owns q rows q0 + w*16 .. +15 (lane col = l16)
    const float QSCALE = 0.125f * 1.44269504088896f;
    short8 qf[2];
#pragma unroll
    for (int c = 0; c < 2; ++c) {
        short8 raw = *(const short8*)&Qb[(size_t)(q0 + w * 16 + l16) * 64 + c * 32 + lg * 8];
#pragma unroll
        for (int j = 0; j < 8; ++j)
            ((ushort*)&qf[c])[j] = f2bf(bf2f(((ushort*)&raw)[j]) * QSCALE);
    }

    floatx4 ob[4];
#pragma unroll
    for (int d = 0; d < 4; ++d) ob[d] = (floatx4){0.f, 0.f, 0.f, 0.f};
    float m = -1e30f, ln = 0.f;

    // block-wide staging: 512 threads x 16B = one 64x64 bf16 tile each for K,V
    int rrow = t >> 3, rcb = (t & 7) * 8;

    short8 kpre, vpre;
    kpre = *(const short8*)&Kb[(size_t)rrow * 64 + rcb];
    vpre = *(const short8*)&Vb[(size_t)rrow * NS + rcb];
    *(short8*)((char*)k_lds[0] + SWZ(rrow, rcb * 2)) = kpre;
    *(short8*)((char*)v_lds[0] + SWZ(rrow, rcb * 2)) = vpre;

    int nt  = 2 * tq + 2;          // kv tiles 0 .. 2tq+1
    int lim = 2 * tq + wh;         // this wave's last (diagonal) tile

    for (int it = 0; it < nt; ++it) {
        __syncthreads();           // buf[it&1] ready; prior reads of buf[nxt] done
        int cur = it & 1, nxt = cur ^ 1;
        bool have_next = (it + 1 < nt);
        if (have_next) {           // issue loads early (hide under compute)
            kpre = *(const short8*)&Kb[(size_t)((it + 1) * 64 + rrow) * 64 + rcb];
            vpre = *(const short8*)&Vb[(size_t)rrow * NS + (it + 1) * 64 + rcb];
        }

        if (it <= lim) {
            // ---- S^T: sv[stt][r] = S[k=stt*16+lg*4+r][q=l16] (log2 dom.)
            floatx4 sv[4];
#pragma unroll
            for (int stt = 0; stt < 4; ++stt) {
                floatx4 acc = {0.f, 0.f, 0.f, 0.f};
#pragma unroll
                for (int c = 0; c < 2; ++c) {
                    int row = stt * 16 + l16;
                    short8 kf = *(const short8*)((const char*)k_lds[cur] +
                                                 SWZ(row, c * 64 + lg * 16));
                    acc = __builtin_amdgcn_mfma_f32_16x16x32_bf16(kf, qf[c], acc, 0, 0, 0);
                }
                sv[stt] = acc;
            }
            if (it == lim) {       // diagonal tile for this wave
#pragma unroll
                for (int stt = 0; stt < 4; ++stt)
#pragma unroll
                    for (int r = 0; r < 4; ++r)
                        if (stt * 16 + lg * 4 + r > w4 * 16 + l16) sv[stt][r] = -1e30f;
            }

            // ---- softmax: in-register 16-max + 2 shuffles ----
            float p01 = fmaxf(fmaxf(sv[0][0], sv[0][1]), fmaxf(sv[0][2], sv[0][3]));
            float p23 = fmaxf(fmaxf(sv[1][0], sv[1][1]), fmaxf(sv[1][2], sv[1][3]));
            float p45 = fmaxf(fmaxf(sv[2][0], sv[2][1]), fmaxf(sv[2][2], sv[2][3]));
            float p67 = fmaxf(fmaxf(sv[3][0], sv[3][1]), fmaxf(sv[3][2], sv[3][3]));
            float pmax = fmaxf(fmaxf(p01, p23), fmaxf(p45, p67));
            pmax = fmaxf(pmax, __shfl_xor(pmax, 16, 64));
            pmax = fmaxf(pmax, __shfl_xor(pmax, 32, 64));

            if (!__all(pmax - m <= 8.0f)) {   // T13 defer-max (log2 units)
                float mn = fmaxf(m, pmax);
                float al = exp2f(m - mn);
                m = mn;
                ln *= al;
#pragma unroll
                for (int d = 0; d < 4; ++d)
#pragma unroll
                    for (int r = 0; r < 4; ++r) ob[d][r] *= al;
            }

            float rs = 0.f;
#pragma unroll
            for (int stt = 0; stt < 4; ++stt)
#pragma unroll
                for (int r = 0; r < 4; ++r) {
                    float p = exp2f(sv[stt][r] - m);
                    sv[stt][r] = p;
                    rs += p;
                }
            rs += __shfl_xor(rs, 16, 64);
            rs += __shfl_xor(rs, 32, 64);
            ln += rs;

            // ---- P -> p_lds[q][k], then PV: O^T = V^T P ----
#pragma unroll
            for (int stt = 0; stt < 4; ++stt) {
                ushort4 pk;
                pk.x = f2bf(sv[stt][0]); pk.y = f2bf(sv[stt][1]);
                pk.z = f2bf(sv[stt][2]); pk.w = f2bf(sv[stt][3]);
                *(ushort4*)&p_lds[w][l16 * 72 + stt * 16 + lg * 4] = pk;
            }

#pragma unroll
            for (int ks = 0; ks < 2; ++ks) {
                short8 pf = *(const short8*)((const char*)&p_lds[w][0] +
                                             (l16 * 144 + ks * 64 + lg * 16));
#pragma unroll
                for (int d = 0; d < 4; ++d) {
                    int vrow = d * 16 + l16;
                    short8 vf = *(const short8*)((const char*)v_lds[cur] +
                                                 SWZ(vrow, ks * 64 + lg * 16));
                    ob[d] = __builtin_amdgcn_mfma_f32_16x16x32_bf16(vf, pf, ob[d], 0, 0, 0);
                }
            }
        }

        if (have_next) {           // write prefetched tile into the other buffer
            *(short8*)((char*)k_lds[nxt] + SWZ(rrow, rcb * 2)) = kpre;
            *(short8*)((char*)v_lds[nxt] + SWZ(rrow, rcb * 2)) = vpre;
        }
    }

    // epilogue: lane owns q = q0 + w*16 + l16; d = d0*16 + lg*4 + r
    float inv = 1.0f / ln;
    int qq = q0 + w * 16 + l16;
#pragma unroll
    for (int d = 0; d < 4; ++d) {
        ushort4 ov;
        ov.x = f2bf(ob[d][0] * inv);
        ov.y = f2bf(ob[d][1] * inv);
        ov.z = f2bf(ob[d][2] * inv);
        ov.w = f2bf(ob[d][3] * inv);
        *(ushort4*)&A[(size_t)(b * NS + qq) * NEMB + h * 64 + d * 16 + lg * 4] = ov;
    }
}

// ---------------------------------------------------------------------------
// Kernel 3: Y = A @ Wo^T + bo via bf16 MFMA, fp32 accum. (unchanged)
// ---------------------------------------------------------------------------
__global__ __launch_bounds__(256) void out_gemm_mfma(
    const ushort* __restrict__ Aq, const ushort* __restrict__ Wob,
    const float* __restrict__ bo, float* __restrict__ Y)
{
    int m0 = blockIdx.x * 128;
    int n0 = blockIdx.y * 128;

    __shared__ __align__(16) ushort As[128 * 64];
    __shared__ __align__(16) ushort Bs[128 * 64];

    int t = threadIdx.x, w = t >> 6, l = t & 63;
    int l16 = l & 15, lg = l >> 4;
    int wr = w >> 1, wc = w & 1;

    floatx4 acc[4][4];
#pragma unroll
    for (int i = 0; i < 4; ++i)
#pragma unroll
        for (int j = 0; j < 4; ++j) acc[i][j] = (floatx4){0.f, 0.f, 0.f, 0.f};

    for (int kt = 0; kt < 16; ++kt) {
        __syncthreads();
#pragma unroll
        for (int i = 0; i < 4; ++i) {
            int chunk = i * 256 + t;
            int row   = chunk >> 3;
            int c16   = chunk & 7;
            short8 av = *(const short8*)&Aq[(size_t)(m0 + row) * 1024 + kt * 64 + c16 * 8];
            *(short8*)((char*)As + SWZ(row, c16 * 16)) = av;
            short8 bv = *(const short8*)&Wob[(size_t)(n0 + row) * 1024 + kt * 64 + c16 * 8];
            *(short8*)((char*)Bs + SWZ(row, c16 * 16)) = bv;
        }
        __syncthreads();
#pragma unroll
        for (int kc = 0; kc < 2; ++kc) {
            short8 af[4], bf[4];
#pragma unroll
            for (int i = 0; i < 4; ++i) {
                int arow = wr * 64 + i * 16 + l16;
                af[i] = *(const short8*)((const char*)As + SWZ(arow, kc * 64 + lg * 16));
                int brow = wc * 64 + i * 16 + l16;
                bf[i] = *(const short8*)((const char*)Bs + SWZ(brow, kc * 64 + lg * 16));
            }
#pragma unroll
            for (int i = 0; i < 4; ++i)
#pragma unroll
                for (int j = 0; j < 4; ++j)
                    acc[i][j] = __builtin_amdgcn_mfma_f32_16x16x32_bf16(
                        af[i], bf[j], acc[i][j], 0, 0, 0);
        }
    }
#pragma unroll
    for (int i = 0; i < 4; ++i)
#pragma unroll
        for (int j = 0; j < 4; ++j) {
            int nn = n0 + wc * 64 + j * 16 + l16;
            float bb = bo[nn];
#pragma unroll
            for (int r = 0; r < 4; ++r) {
                int mm = m0 + wr * 64 + i * 16 + lg * 4 + r;
                Y[(size_t)mm * 1024 + nn] = acc[i][j][r] + bb;
            }
        }
}

// ---------------------------------------------------------------------------
extern "C" void kernel_launch(void* const* d_in, const int* in_sizes, int n_in,
                              void* d_out, int out_size, void* d_ws, size_t ws_size,
                              hipStream_t stream) {
    const float* X  = (const float*)d_in[0];
    const float* Z  = (const float*)d_in[1];
    const float* Wq = (const float*)d_in[2];
    const float* bq = (const float*)d_in[3];
    const float* Wk = (const float*)d_in[4];
    const float* bk = (const float*)d_in[5];
    const float* Wv = (const float*)d_in[6];
    const float* bv = (const float*)d_in[7];
    const float* Wo = (const float*)d_in[8];
    const float* bo = (const float*)d_in[9];
    float* out = (float*)d_out;

    const size_t NQ = (size_t)NB * NH * NS * NHD;   // 4M elems
    ushort* Qd  = (ushort*)d_ws;
    ushort* Kd  = Qd + NQ;
    ushort* Vtd = Kd + NQ;
    ushort* Ad  = Vtd + NQ;
    ushort* Wob = Ad + NQ;

    qkv_mfma<<<dim3(NS / 128, NB * NH), 256, 0, stream>>>(
        X, Z, Wq, bq, Wk, bk, Wv, bv, Qd, Kd, Vtd);
    wo_cast<<<dim3(512), 256, 0, stream>>>(Wo, Wob);
    flash_attn<<<dim3(NS / 128, NB * NH), 512, 0, stream>>>(Qd, Kd, Vtd, Ad);
    out_gemm_mfma<<<dim3(32, 8), 256, 0, stream>>>(Ad, Wob, bo, out);
}

// Round 9
// 109.409 us; speedup vs baseline: 61.4346x; 1.0329x over previous
//
#include <hip/hip_runtime.h>
#include <hip/hip_bf16.h>
#include <math.h>

#define NB   2
#define NS   2048
#define NEMB 1024
#define NH   16
#define NHD  64

typedef __attribute__((ext_vector_type(8))) short short8;
typedef __attribute__((ext_vector_type(4))) float floatx4;

static __device__ __forceinline__ ushort f2bf(float f) {
    union { float f; uint u; } x; x.f = f;
    uint r = (x.u + 0x7FFFu + ((x.u >> 16) & 1u)) >> 16;
    return (ushort)r;
}
static __device__ __forceinline__ float bf2f(ushort u) {
    union { uint u; float f; } x; x.u = ((uint)u) << 16;
    return x.f;
}
// HW packed convert: dword = [bf16(lo) | bf16(hi)<<16]  (1 instr vs ~10)
static __device__ __forceinline__ uint cvt_pk(float lo, float hi) {
    uint r;
    asm("v_cvt_pk_bf16_f32 %0, %1, %2" : "=v"(r) : "v"(lo), "v"(hi));
    return r;
}

#define SWZ(row, bytecol) (((row) * 128 + (bytecol)) ^ (((row) & 7) << 4))

// ---------------------------------------------------------------------------
// Kernel 1: fused QKV projection via MFMA (fp32 in, bf16 out), emits Q, K and
// TRANSPOSED V (Vt[b,h,d,s]) directly. grid = (S/128, B*H), block 256.
// ---------------------------------------------------------------------------
__global__ __launch_bounds__(256) void qkv_mfma(
    const float* __restrict__ X, const float* __restrict__ Z,
    const float* __restrict__ Wq, const float* __restrict__ bq,
    const float* __restrict__ Wk, const float* __restrict__ bk,
    const float* __restrict__ Wv, const float* __restrict__ bv,
    ushort* __restrict__ Q, ushort* __restrict__ K, ushort* __restrict__ Vt)
{
    int st = blockIdx.x, bh = blockIdx.y;
    int h = bh & (NH - 1), b = bh >> 4;
    int s0 = st * 128;

    __shared__ __align__(16) ushort xs[128 * 72];
    __shared__ __align__(16) ushort zs[128 * 72];
    __shared__ __align__(16) ushort wqs[64 * 64], wks[64 * 64], wvs[64 * 64];

    int t = threadIdx.x, w = t >> 6, l = t & 63;
    int l16 = l & 15, lg = l >> 4;

#pragma unroll
    for (int c = 0; c < 4; ++c) {
        int chunk = c * 256 + t;
        int row   = chunk >> 3;
        int c8    = chunk & 7;
        const float* px = &X[(size_t)(b * NS + s0 + row) * NEMB + h * 64 + c8 * 8];
        const float* pz = &Z[(size_t)(b * NS + s0 + row) * NEMB + h * 64 + c8 * 8];
        float4 a0 = *(const float4*)px, a1 = *(const float4*)(px + 4);
        float4 z0 = *(const float4*)pz, z1 = *(const float4*)(pz + 4);
        short8 xv, zv;
        ((uint*)&xv)[0] = cvt_pk(a0.x, a0.y);
        ((uint*)&xv)[1] = cvt_pk(a0.z, a0.w);
        ((uint*)&xv)[2] = cvt_pk(a1.x, a1.y);
        ((uint*)&xv)[3] = cvt_pk(a1.z, a1.w);
        ((uint*)&zv)[0] = cvt_pk(z0.x, z0.y);
        ((uint*)&zv)[1] = cvt_pk(z0.z, z0.w);
        ((uint*)&zv)[2] = cvt_pk(z1.x, z1.y);
        ((uint*)&zv)[3] = cvt_pk(z1.z, z1.w);
        *(short8*)((char*)xs + SWZ(row, c8 * 16)) = xv;
        *(short8*)((char*)zs + SWZ(row, c8 * 16)) = zv;
    }
#pragma unroll
    for (int c = 0; c < 2; ++c) {
        int chunk = c * 256 + t;
        int row   = chunk >> 3;
        int c8    = chunk & 7;
        const float* pq = &Wq[(size_t)h * 4096 + row * 64 + c8 * 8];
        const float* pk = &Wk[(size_t)h * 4096 + row * 64 + c8 * 8];
        const float* pv = &Wv[(size_t)h * 4096 + row * 64 + c8 * 8];
        float4 q0 = *(const float4*)pq, q1 = *(const float4*)(pq + 4);
        float4 k0 = *(const float4*)pk, k1 = *(const float4*)(pk + 4);
        float4 v0 = *(const float4*)pv, v1 = *(const float4*)(pv + 4);
        short8 qv, kv, vv;
        ((uint*)&qv)[0] = cvt_pk(q0.x, q0.y); ((uint*)&qv)[1] = cvt_pk(q0.z, q0.w);
        ((uint*)&qv)[2] = cvt_pk(q1.x, q1.y); ((uint*)&qv)[3] = cvt_pk(q1.z, q1.w);
        ((uint*)&kv)[0] = cvt_pk(k0.x, k0.y); ((uint*)&kv)[1] = cvt_pk(k0.z, k0.w);
        ((uint*)&kv)[2] = cvt_pk(k1.x, k1.y); ((uint*)&kv)[3] = cvt_pk(k1.z, k1.w);
        ((uint*)&vv)[0] = cvt_pk(v0.x, v0.y); ((uint*)&vv)[1] = cvt_pk(v0.z, v0.w);
        ((uint*)&vv)[2] = cvt_pk(v1.x, v1.y); ((uint*)&vv)[3] = cvt_pk(v1.z, v1.w);
        *(short8*)((char*)wqs + SWZ(row, c8 * 16)) = qv;
        *(short8*)((char*)wks + SWZ(row, c8 * 16)) = kv;
        *(short8*)((char*)wvs + SWZ(row, c8 * 16)) = vv;
    }
    __syncthreads();

    floatx4 aq[2][4], ak[2][4], av[2][4];
#pragma unroll
    for (int i = 0; i < 2; ++i)
#pragma unroll
        for (int j = 0; j < 4; ++j) {
            aq[i][j] = (floatx4){0.f, 0.f, 0.f, 0.f};
            ak[i][j] = (floatx4){0.f, 0.f, 0.f, 0.f};
            av[i][j] = (floatx4){0.f, 0.f, 0.f, 0.f};
        }

#pragma unroll
    for (int kc = 0; kc < 2; ++kc) {
        short8 xa[2], za[2];
#pragma unroll
        for (int i = 0; i < 2; ++i) {
            int row = w * 32 + i * 16 + l16;
            xa[i] = *(const short8*)((const char*)xs + SWZ(row, kc * 64 + lg * 16));
            za[i] = *(const short8*)((const char*)zs + SWZ(row, kc * 64 + lg * 16));
        }
#pragma unroll
        for (int j = 0; j < 4; ++j) {
            int row = j * 16 + l16;
            short8 wqf = *(const short8*)((const char*)wqs + SWZ(row, kc * 64 + lg * 16));
            short8 wkf = *(const short8*)((const char*)wks + SWZ(row, kc * 64 + lg * 16));
            short8 wvf = *(const short8*)((const char*)wvs + SWZ(row, kc * 64 + lg * 16));
#pragma unroll
            for (int i = 0; i < 2; ++i) {
                aq[i][j] = __builtin_amdgcn_mfma_f32_16x16x32_bf16(xa[i], wqf, aq[i][j], 0, 0, 0);
                ak[i][j] = __builtin_amdgcn_mfma_f32_16x16x32_bf16(za[i], wkf, ak[i][j], 0, 0, 0);
                av[i][j] = __builtin_amdgcn_mfma_f32_16x16x32_bf16(za[i], wvf, av[i][j], 0, 0, 0);
            }
        }
    }

    float bqv[4], bkv[4], bvv[4];
#pragma unroll
    for (int j = 0; j < 4; ++j) {
        bqv[j] = bq[h * 64 + j * 16 + l16];
        bkv[j] = bk[h * 64 + j * 16 + l16];
        bvv[j] = bv[h * 64 + j * 16 + l16];
    }

#pragma unroll
    for (int i = 0; i < 2; ++i)
#pragma unroll
        for (int j = 0; j < 4; ++j) {
            int d = j * 16 + l16;
            int s = s0 + w * 32 + i * 16 + lg * 4;
            uint2 pv2;
            pv2.x = cvt_pk(av[i][j][0] + bvv[j], av[i][j][1] + bvv[j]);
            pv2.y = cvt_pk(av[i][j][2] + bvv[j], av[i][j][3] + bvv[j]);
            *(uint2*)&Vt[((size_t)bh * NHD + d) * NS + s] = pv2;
        }

    __syncthreads();
#pragma unroll
    for (int i = 0; i < 2; ++i)
#pragma unroll
        for (int j = 0; j < 4; ++j)
#pragma unroll
            for (int r = 0; r < 4; r += 2) {
                int sA = w * 32 + i * 16 + lg * 4 + r;
                uint uq = cvt_pk(aq[i][j][r] + bqv[j], aq[i][j][r + 1] + bqv[j]);
                uint uk = cvt_pk(ak[i][j][r] + bkv[j], ak[i][j][r + 1] + bkv[j]);
                xs[sA * 72 + j * 16 + l16]       = (ushort)uq;
                xs[(sA + 1) * 72 + j * 16 + l16] = (ushort)(uq >> 16);
                zs[sA * 72 + j * 16 + l16]       = (ushort)uk;
                zs[(sA + 1) * 72 + j * 16 + l16] = (ushort)(uk >> 16);
            }
    __syncthreads();
#pragma unroll
    for (int c = 0; c < 4; ++c) {
        int chunk = c * 256 + t;
        int row   = chunk >> 3;
        int c8    = chunk & 7;
        short8 qv = *(const short8*)&xs[row * 72 + c8 * 8];
        short8 kv = *(const short8*)&zs[row * 72 + c8 * 8];
        *(short8*)&Q[((size_t)bh * NS + s0 + row) * 64 + c8 * 8] = qv;
        *(short8*)&K[((size_t)bh * NS + s0 + row) * 64 + c8 * 8] = kv;
    }
}

// ---------------------------------------------------------------------------
// Kernel 1c: Wo fp32 -> bf16.
// ---------------------------------------------------------------------------
__global__ __launch_bounds__(256) void wo_cast(
    const float* __restrict__ Wo, ushort* __restrict__ Wob)
{
    int i = (blockIdx.x * 256 + threadIdx.x) * 8;
    float4 a = *(const float4*)&Wo[i];
    float4 b = *(const float4*)&Wo[i + 4];
    short8 o;
    ((uint*)&o)[0] = cvt_pk(a.x, a.y);
    ((uint*)&o)[1] = cvt_pk(a.z, a.w);
    ((uint*)&o)[2] = cvt_pk(b.x, b.y);
    ((uint*)&o)[3] = cvt_pk(b.z, b.w);
    *(short8*)&Wob[i] = o;
}

// ---------------------------------------------------------------------------
// Kernel 2: MFMA flash attention, swapped operands, Q-pair sharing (8 waves,
// 128 q rows, one shared K/V tile per epoch, double-buffered, 1 barrier).
// This round: all fp32->bf16 through v_cvt_pk_bf16_f32 (P-pack 88->12 VALU).
// ---------------------------------------------------------------------------
__global__ __launch_bounds__(512) void flash_attn(
    const ushort* __restrict__ Q, const ushort* __restrict__ K,
    const ushort* __restrict__ Vt, ushort* __restrict__ A)
{
    int tq = (gridDim.x - 1) - blockIdx.x;   // q-pair index, heavy first
    int bh = blockIdx.y;
    int h = bh & (NH - 1), b = bh >> 4;

    __shared__ __align__(16) ushort k_lds[2][64 * 64];
    __shared__ __align__(16) ushort v_lds[2][64 * 64];
    __shared__ __align__(16) ushort p_lds[8][16 * 72];

    int t = threadIdx.x, w = t >> 6, l = t & 63;
    int l16 = l & 15, lg = l >> 4;
    int w4 = w & 3, wh = w >> 2;

    const ushort* Qb = Q + (size_t)bh * NS * NHD;
    const ushort* Kb = K + (size_t)bh * NS * NHD;
    const ushort* Vb = Vt + (size_t)bh * NHD * NS;

    int q0 = tq * 128;

    // Q fragment: wave w owns q rows q0 + w*16 .. +15 (lane col = l16)
    const float QSCALE = 0.125f * 1.44269504088896f;
    short8 qf[2];
#pragma unroll
    for (int c = 0; c < 2; ++c) {
        short8 raw = *(const short8*)&Qb[(size_t)(q0 + w * 16 + l16) * 64 + c * 32 + lg * 8];
#pragma unroll
        for (int j = 0; j < 4; ++j)
            ((uint*)&qf[c])[j] = cvt_pk(bf2f(((ushort*)&raw)[2 * j]) * QSCALE,
                                        bf2f(((ushort*)&raw)[2 * j + 1]) * QSCALE);
    }

    floatx4 ob[4];
#pragma unroll
    for (int d = 0; d < 4; ++d) ob[d] = (floatx4){0.f, 0.f, 0.f, 0.f};
    float m = -1e30f, ln = 0.f;

    // block-wide staging: 512 threads x 16B = one 64x64 bf16 tile each for K,V
    int rrow = t >> 3, rcb = (t & 7) * 8;

    short8 kpre, vpre;
    kpre = *(const short8*)&Kb[(size_t)rrow * 64 + rcb];
    vpre = *(const short8*)&Vb[(size_t)rrow * NS + rcb];
    *(short8*)((char*)k_lds[0] + SWZ(rrow, rcb * 2)) = kpre;
    *(short8*)((char*)v_lds[0] + SWZ(rrow, rcb * 2)) = vpre;

    int nt  = 2 * tq + 2;          // kv tiles 0 .. 2tq+1
    int lim = 2 * tq + wh;         // this wave's last (diagonal) tile

    for (int it = 0; it < nt; ++it) {
        __syncthreads();           // buf[it&1] ready; prior reads of buf[nxt] done
        int cur = it & 1, nxt = cur ^ 1;
        bool have_next = (it + 1 < nt);
        if (have_next) {           // issue loads early (hide under compute)
            kpre = *(const short8*)&Kb[(size_t)((it + 1) * 64 + rrow) * 64 + rcb];
            vpre = *(const short8*)&Vb[(size_t)rrow * NS + (it + 1) * 64 + rcb];
        }

        if (it <= lim) {
            // ---- S^T: sv[stt][r] = S[k=stt*16+lg*4+r][q=l16] (log2 dom.)
            floatx4 sv[4];
#pragma unroll
            for (int stt = 0; stt < 4; ++stt) {
                floatx4 acc = {0.f, 0.f, 0.f, 0.f};
#pragma unroll
                for (int c = 0; c < 2; ++c) {
                    int row = stt * 16 + l16;
                    short8 kf = *(const short8*)((const char*)k_lds[cur] +
                                                 SWZ(row, c * 64 + lg * 16));
                    acc = __builtin_amdgcn_mfma_f32_16x16x32_bf16(kf, qf[c], acc, 0, 0, 0);
                }
                sv[stt] = acc;
            }
            if (it == lim) {       // diagonal tile for this wave
#pragma unroll
                for (int stt = 0; stt < 4; ++stt)
#pragma unroll
                    for (int r = 0; r < 4; ++r)
                        if (stt * 16 + lg * 4 + r > w4 * 16 + l16) sv[stt][r] = -1e30f;
            }

            // ---- softmax: in-register 16-max + 2 shuffles ----
            float p01 = fmaxf(fmaxf(sv[0][0], sv[0][1]), fmaxf(sv[0][2], sv[0][3]));
            float p23 = fmaxf(fmaxf(sv[1][0], sv[1][1]), fmaxf(sv[1][2], sv[1][3]));
            float p45 = fmaxf(fmaxf(sv[2][0], sv[2][1]), fmaxf(sv[2][2], sv[2][3]));
            float p67 = fmaxf(fmaxf(sv[3][0], sv[3][1]), fmaxf(sv[3][2], sv[3][3]));
            float pmax = fmaxf(fmaxf(p01, p23), fmaxf(p45, p67));
            pmax = fmaxf(pmax, __shfl_xor(pmax, 16, 64));
            pmax = fmaxf(pmax, __shfl_xor(pmax, 32, 64));

            if (!__all(pmax - m <= 8.0f)) {   // T13 defer-max (log2 units)
                float mn = fmaxf(m, pmax);
                float al = exp2f(m - mn);
                m = mn;
                ln *= al;
#pragma unroll
                for (int d = 0; d < 4; ++d)
#pragma unroll
                    for (int r = 0; r < 4; ++r) ob[d][r] *= al;
            }

            float rs = 0.f;
#pragma unroll
            for (int stt = 0; stt < 4; ++stt)
#pragma unroll
                for (int r = 0; r < 4; ++r) {
                    float p = exp2f(sv[stt][r] - m);
                    sv[stt][r] = p;
                    rs += p;
                }
            rs += __shfl_xor(rs, 16, 64);
            rs += __shfl_xor(rs, 32, 64);
            ln += rs;

            // ---- P -> p_lds[q][k] via packed cvt, then PV: O^T = V^T P ----
#pragma unroll
            for (int stt = 0; stt < 4; ++stt) {
                uint2 pk2;
                pk2.x = cvt_pk(sv[stt][0], sv[stt][1]);
                pk2.y = cvt_pk(sv[stt][2], sv[stt][3]);
                *(uint2*)&p_lds[w][l16 * 72 + stt * 16 + lg * 4] = pk2;
            }

#pragma unroll
            for (int ks = 0; ks < 2; ++ks) {
                short8 pf = *(const short8*)((const char*)&p_lds[w][0] +
                                             (l16 * 144 + ks * 64 + lg * 16));
#pragma unroll
                for (int d = 0; d < 4; ++d) {
                    int vrow = d * 16 + l16;
                    short8 vf = *(const short8*)((const char*)v_lds[cur] +
                                                 SWZ(vrow, ks * 64 + lg * 16));
                    ob[d] = __builtin_amdgcn_mfma_f32_16x16x32_bf16(vf, pf, ob[d], 0, 0, 0);
                }
            }
        }

        if (have_next) {           // write prefetched tile into the other buffer
            *(short8*)((char*)k_lds[nxt] + SWZ(rrow, rcb * 2)) = kpre;
            *(short8*)((char*)v_lds[nxt] + SWZ(rrow, rcb * 2)) = vpre;
        }
    }

    // epilogue: lane owns q = q0 + w*16 + l16; d = d0*16 + lg*4 + r
    float inv = 1.0f / ln;
    int qq = q0 + w * 16 + l16;
#pragma unroll
    for (int d = 0; d < 4; ++d) {
        uint2 ov;
        ov.x = cvt_pk(ob[d][0] * inv, ob[d][1] * inv);
        ov.y = cvt_pk(ob[d][2] * inv, ob[d][3] * inv);
        *(uint2*)&A[(size_t)(b * NS + qq) * NEMB + h * 64 + d * 16 + lg * 4] = ov;
    }
}

// ---------------------------------------------------------------------------
// Kernel 3: Y = A @ Wo^T + bo via bf16 MFMA, fp32 accum. (unchanged)
// ---------------------------------------------------------------------------
__global__ __launch_bounds__(256) void out_gemm_mfma(
    const ushort* __restrict__ Aq, const ushort* __restrict__ Wob,
    const float* __restrict__ bo, float* __restrict__ Y)
{
    int m0 = blockIdx.x * 128;
    int n0 = blockIdx.y * 128;

    __shared__ __align__(16) ushort As[128 * 64];
    __shared__ __align__(16) ushort Bs[128 * 64];

    int t = threadIdx.x, w = t >> 6, l = t & 63;
    int l16 = l & 15, lg = l >> 4;
    int wr = w >> 1, wc = w & 1;

    floatx4 acc[4][4];
#pragma unroll
    for (int i = 0; i < 4; ++i)
#pragma unroll
        for (int j = 0; j < 4; ++j) acc[i][j] = (floatx4){0.f, 0.f, 0.f, 0.f};

    for (int kt = 0; kt < 16; ++kt) {
        __syncthreads();
#pragma unroll
        for (int i = 0; i < 4; ++i) {
            int chunk = i * 256 + t;
            int row   = chunk >> 3;
            int c16   = chunk & 7;
            short8 av = *(const short8*)&Aq[(size_t)(m0 + row) * 1024 + kt * 64 + c16 * 8];
            *(short8*)((char*)As + SWZ(row, c16 * 16)) = av;
            short8 bv = *(const short8*)&Wob[(size_t)(n0 + row) * 1024 + kt * 64 + c16 * 8];
            *(short8*)((char*)Bs + SWZ(row, c16 * 16)) = bv;
        }
        __syncthreads();
#pragma unroll
        for (int kc = 0; kc < 2; ++kc) {
            short8 af[4], bf[4];
#pragma unroll
            for (int i = 0; i < 4; ++i) {
                int arow = wr * 64 + i * 16 + l16;
                af[i] = *(const short8*)((const char*)As + SWZ(arow, kc * 64 + lg * 16));
                int brow = wc * 64 + i * 16 + l16;
                bf[i] = *(const short8*)((const char*)Bs + SWZ(brow, kc * 64 + lg * 16));
            }
#pragma unroll
            for (int i = 0; i < 4; ++i)
#pragma unroll
                for (int j = 0; j < 4; ++j)
                    acc[i][j] = __builtin_amdgcn_mfma_f32_16x16x32_bf16(
                        af[i], bf[j], acc[i][j], 0, 0, 0);
        }
    }
#pragma unroll
    for (int i = 0; i < 4; ++i)
#pragma unroll
        for (int j = 0; j < 4; ++j) {
            int nn = n0 + wc * 64 + j * 16 + l16;
            float bb = bo[nn];
#pragma unroll
            for (int r = 0; r < 4; ++r) {
                int mm = m0 + wr * 64 + i * 16 + lg * 4 + r;
                Y[(size_t)mm * 1024 + nn] = acc[i][j][r] + bb;
            }
        }
}

// ---------------------------------------------------------------------------
extern "C" void kernel_launch(void* const* d_in, const int* in_sizes, int n_in,
                              void* d_out, int out_size, void* d_ws, size_t ws_size,
                              hipStream_t stream) {
    const float* X  = (const float*)d_in[0];
    const float* Z  = (const float*)d_in[1];
    const float* Wq = (const float*)d_in[2];
    const float* bq = (const float*)d_in[3];
    const float* Wk = (const float*)d_in[4];
    const float* bk = (const float*)d_in[5];
    const float* Wv = (const float*)d_in[6];
    const float* bv = (const float*)d_in[7];
    const float* Wo = (const float*)d_in[8];
    const float* bo = (const float*)d_in[9];
    float* out = (float*)d_out;

    const size_t NQ = (size_t)NB * NH * NS * NHD;   // 4M elems
    ushort* Qd  = (ushort*)d_ws;
    ushort* Kd  = Qd + NQ;
    ushort* Vtd = Kd + NQ;
    ushort* Ad  = Vtd + NQ;
    ushort* Wob = Ad + NQ;

    qkv_mfma<<<dim3(NS / 128, NB * NH), 256, 0, stream>>>(
        X, Z, Wq, bq, Wk, bk, Wv, bv, Qd, Kd, Vtd);
    wo_cast<<<dim3(512), 256, 0, stream>>>(Wo, Wob);
    flash_attn<<<dim3(NS / 128, NB * NH), 512, 0, stream>>>(Qd, Kd, Vtd, Ad);
    out_gemm_mfma<<<dim3(32, 8), 256, 0, stream>>>(Ad, Wob, bo, out);
}